// Round 1
// baseline (50045.963 us; speedup 1.0000x reference)
//
#include <hip/hip_runtime.h>
#include <hip/hip_bf16.h>

typedef __hip_bfloat16 bf16;
typedef __attribute__((ext_vector_type(8))) short short8;
typedef __attribute__((ext_vector_type(4))) float f32x4;

#define T_ 256
#define B_ 64
#define V_ 10000
#define E_ 400
#define H_ 1152

// padded K dims (multiples of 32)
#define K0 1568   // 400 xe + 16 pad + 1152 h0   (13 + 36 k-tiles)
#define K1 2304   // 1152 h0 + 1152 h1           (72 k-tiles)
#define K2 1568   // 1152 h1 + 400 h2 + 16 pad   (49 k-tiles)
#define KD 416    // 400 + 16 pad                (13 k-tiles)
#define XW 416    // padded embedding width

// ---------------- prep kernels ----------------

// dst[n][k] (bf16): k<w1 -> s1[n*w1+k]; s2off<=k<s2off+w2 -> s2[n*w2+k-s2off]; else 0
__global__ __launch_bounds__(256) void prep_wcat(
    const float* __restrict__ s1, int w1,
    const float* __restrict__ s2, int w2, int s2off,
    bf16* __restrict__ dst, int Ktot, long total)
{
    long i = (long)blockIdx.x * 256 + threadIdx.x;
    if (i >= total) return;
    int n = (int)(i / Ktot), k = (int)(i % Ktot);
    float v = 0.f;
    if (k < w1) v = s1[(long)n * w1 + k];
    else if (k >= s2off && k < s2off + w2) v = s2[(long)n * w2 + (k - s2off)];
    dst[i] = __float2bfloat16(v);
}

__global__ __launch_bounds__(256) void bias_add(
    const float* __restrict__ a, const float* __restrict__ b,
    float* __restrict__ d, int n)
{
    int i = blockIdx.x * 256 + threadIdx.x;
    if (i < n) d[i] = a[i] + b[i];
}

__global__ __launch_bounds__(256) void gather_xe(
    const int* __restrict__ x, const float* __restrict__ emb,
    bf16* __restrict__ xe)
{
    long i = (long)blockIdx.x * 256 + threadIdx.x;
    if (i >= (long)T_ * B_ * XW) return;
    int k = (int)(i % XW);
    long tb = i / XW;
    float v = 0.f;
    if (k < E_) v = emb[(long)x[tb] * E_ + k];
    xe[i] = __float2bfloat16(v);
}

// strided fp32 -> bf16 copy into an activation buffer region
__global__ __launch_bounds__(256) void copy_h(
    const float* __restrict__ src, bf16* __restrict__ dst,
    int cols, int dstride, int doff, int total)
{
    int i = blockIdx.x * 256 + threadIdx.x;
    if (i >= total) return;
    int r = i / cols, c = i % cols;
    dst[(long)r * dstride + doff + c] = __float2bfloat16(src[i]);
}

__global__ __launch_bounds__(256) void copy_f32(
    const float* __restrict__ src, float* __restrict__ dst, int n)
{
    int i = blockIdx.x * 256 + threadIdx.x;
    if (i < n) dst[i] = src[i];
}

// ---------------- fused LSTM layer step ----------------
// grid.x = Hlayer/16 strips; 256 threads = 4 waves; wave g handles gate g.
// gates[64 rows][16 cols of strip] per gate via MFMA, then LDS exchange,
// nonlinearity, c update, h written (bf16) to two destination buffers.
__global__ __launch_bounds__(256) void lstm_layer(
    const bf16* __restrict__ Asrc1, int as1_stride, int ktiles1,
    const bf16* __restrict__ Asrc2, int as2_stride, int ktotal,
    const bf16* __restrict__ W, int Wstride, const float* __restrict__ bias,
    int Hlayer, float* __restrict__ cbuf,
    bf16* __restrict__ dstA, int dstA_stride, int dstA_off,
    bf16* __restrict__ dstB, int dstB_stride, int dstB_off)
{
    __shared__ float gsm[4][64][16];   // [gate][row][col] 16 KB
    const int tid = threadIdx.x;
    const int lane = tid & 63;
    const int g = tid >> 6;            // gate index = wave id
    const int j0 = blockIdx.x * 16;    // strip within hidden dim
    const int c16 = lane & 15;
    const int kg = lane >> 4;          // k-group 0..3

    const bf16* Brow = W + (long)(g * Hlayer + j0 + c16) * Wstride + kg * 8;

    f32x4 acc[4];
    for (int m = 0; m < 4; ++m) acc[m] = (f32x4){0.f, 0.f, 0.f, 0.f};

    for (int kt = 0; kt < ktotal; ++kt) {
        short8 bfrag = *(const short8*)(Brow + kt * 32);
        const bf16* ab; int astr; int kk;
        if (kt < ktiles1) { ab = Asrc1; astr = as1_stride; kk = kt * 32; }
        else             { ab = Asrc2; astr = as2_stride; kk = (kt - ktiles1) * 32; }
        const bf16* abase = ab + kk + kg * 8;
        #pragma unroll
        for (int m = 0; m < 4; ++m) {
            short8 afrag = *(const short8*)(abase + (long)(m * 16 + c16) * astr);
            acc[m] = __builtin_amdgcn_mfma_f32_16x16x32_bf16(afrag, bfrag, acc[m], 0, 0, 0);
        }
    }

    float bv = bias[g * Hlayer + j0 + c16];
    #pragma unroll
    for (int m = 0; m < 4; ++m)
        #pragma unroll
        for (int r = 0; r < 4; ++r)
            gsm[g][m * 16 + kg * 4 + r][c16] = acc[m][r] + bv;

    __syncthreads();

    // nonlinearity: 64 rows x 16 cols = 1024 outputs, 4 per thread
    for (int idx = tid; idx < 1024; idx += 256) {
        int row = idx >> 4, col = idx & 15;
        float ig = gsm[0][row][col];
        float fg = gsm[1][row][col];
        float gg = gsm[2][row][col];
        float og = gsm[3][row][col];
        long cidx = (long)row * Hlayer + j0 + col;
        float c_old = cbuf[cidx];
        float i_s = 1.f / (1.f + expf(-ig));
        float f_s = 1.f / (1.f + expf(-fg));
        float o_s = 1.f / (1.f + expf(-og));
        float c_new = f_s * c_old + i_s * tanhf(gg);
        float h = o_s * tanhf(c_new);
        cbuf[cidx] = c_new;
        bf16 hb = __float2bfloat16(h);
        dstA[(long)row * dstA_stride + dstA_off + j0 + col] = hb;
        dstB[(long)row * dstB_stride + dstB_off + j0 + col] = hb;
    }
}

// ---------------- decoder GEMM ----------------
// C[16384][10000] = A[16384][416]bf16 @ W[10000][416]^T bf16 + b, fp32 out
// block = 4 waves; WG tile 64(M) x 64(N); wave w -> rows w*16..w*16+15
__global__ __launch_bounds__(256) void decoder(
    const bf16* __restrict__ A, const bf16* __restrict__ W,
    const float* __restrict__ bias, float* __restrict__ out)
{
    const int tid = threadIdx.x;
    const int lane = tid & 63;
    const int w = tid >> 6;
    const int n0 = blockIdx.x * 64;
    const int m0 = blockIdx.y * 64 + w * 16;
    const int c16 = lane & 15;
    const int kg = lane >> 4;

    f32x4 acc[4];
    for (int i = 0; i < 4; ++i) acc[i] = (f32x4){0.f, 0.f, 0.f, 0.f};

    const bf16* arow = A + (long)(m0 + c16) * KD + kg * 8;
    #pragma unroll
    for (int kt = 0; kt < 13; ++kt) {
        short8 af = *(const short8*)(arow + kt * 32);
        #pragma unroll
        for (int ns = 0; ns < 4; ++ns) {
            int n = n0 + ns * 16 + c16;
            if (n > V_ - 1) n = V_ - 1;
            short8 bfr = *(const short8*)(W + (long)n * KD + kt * 32 + kg * 8);
            acc[ns] = __builtin_amdgcn_mfma_f32_16x16x32_bf16(af, bfr, acc[ns], 0, 0, 0);
        }
    }

    #pragma unroll
    for (int ns = 0; ns < 4; ++ns) {
        int col = n0 + ns * 16 + c16;
        if (col < V_) {
            float bv = bias[col];
            #pragma unroll
            for (int r = 0; r < 4; ++r) {
                int row = m0 + kg * 4 + r;
                out[(size_t)row * V_ + col] = acc[ns][r] + bv;
            }
        }
    }
}

// ---------------- host ----------------

extern "C" void kernel_launch(void* const* d_in, const int* in_sizes, int n_in,
                              void* d_out, int out_size, void* d_ws, size_t ws_size,
                              hipStream_t stream)
{
    const int*   x    = (const int*)d_in[0];
    const float* h0   = (const float*)d_in[1];
    const float* h1   = (const float*)d_in[2];
    const float* h2   = (const float*)d_in[3];
    const float* c0   = (const float*)d_in[4];
    const float* c1   = (const float*)d_in[5];
    const float* c2   = (const float*)d_in[6];
    const float* emb  = (const float*)d_in[7];
    const float* Wih0 = (const float*)d_in[8];
    const float* Whh0 = (const float*)d_in[9];
    const float* bih0 = (const float*)d_in[10];
    const float* bhh0 = (const float*)d_in[11];
    const float* Wih1 = (const float*)d_in[12];
    const float* Whh1 = (const float*)d_in[13];
    const float* bih1 = (const float*)d_in[14];
    const float* bhh1 = (const float*)d_in[15];
    const float* Wih2 = (const float*)d_in[16];
    const float* Whh2 = (const float*)d_in[17];
    const float* bih2 = (const float*)d_in[18];
    const float* bhh2 = (const float*)d_in[19];
    const float* decW = (const float*)d_in[20];
    const float* decb = (const float*)d_in[21];

    char* wsb = (char*)d_ws;
    size_t off = 0;
    auto alloc = [&](size_t bytes) -> void* {
        void* p = wsb + off;
        off = (off + bytes + 255) & ~(size_t)255;
        return p;
    };

    bf16* W0c = (bf16*)alloc((size_t)4 * H_ * K0 * 2);
    bf16* W1c = (bf16*)alloc((size_t)4 * H_ * K1 * 2);
    bf16* W2c = (bf16*)alloc((size_t)4 * E_ * K2 * 2);
    bf16* Wdc = (bf16*)alloc((size_t)V_ * KD * 2);
    float* b0 = (float*)alloc(4 * H_ * 4);
    float* b1 = (float*)alloc(4 * H_ * 4);
    float* b2 = (float*)alloc(4 * E_ * 4);
    bf16* xe  = (bf16*)alloc((size_t)T_ * B_ * XW * 2);
    bf16* X0h[2] = { (bf16*)alloc((size_t)B_ * H_ * 2), (bf16*)alloc((size_t)B_ * H_ * 2) };
    bf16* X1[2]  = { (bf16*)alloc((size_t)B_ * K1 * 2), (bf16*)alloc((size_t)B_ * K1 * 2) };
    bf16* X2[2]  = { (bf16*)alloc((size_t)B_ * K2 * 2), (bf16*)alloc((size_t)B_ * K2 * 2) };
    float* c0b = (float*)alloc((size_t)B_ * H_ * 4);
    float* c1b = (float*)alloc((size_t)B_ * H_ * 4);
    float* c2b = (float*)alloc((size_t)B_ * E_ * 4);
    bf16* outb = (bf16*)alloc((size_t)T_ * B_ * XW * 2);

    auto cdiv = [](long a, long b) { return (int)((a + b - 1) / b); };

    // weight prep
    prep_wcat<<<cdiv(4608L * K0, 256), 256, 0, stream>>>(Wih0, 400, Whh0, 1152, 416, W0c, K0, 4608L * K0);
    prep_wcat<<<cdiv(4608L * K1, 256), 256, 0, stream>>>(Wih1, 1152, Whh1, 1152, 1152, W1c, K1, 4608L * K1);
    prep_wcat<<<cdiv(1600L * K2, 256), 256, 0, stream>>>(Wih2, 1152, Whh2, 400, 1152, W2c, K2, 1600L * K2);
    prep_wcat<<<cdiv((long)V_ * KD, 256), 256, 0, stream>>>(decW, 400, nullptr, 0, 416, Wdc, KD, (long)V_ * KD);
    bias_add<<<cdiv(4608, 256), 256, 0, stream>>>(bih0, bhh0, b0, 4608);
    bias_add<<<cdiv(4608, 256), 256, 0, stream>>>(bih1, bhh1, b1, 4608);
    bias_add<<<cdiv(1600, 256), 256, 0, stream>>>(bih2, bhh2, b2, 1600);
    gather_xe<<<cdiv((long)T_ * B_ * XW, 256), 256, 0, stream>>>(x, emb, xe);

    // state init
    copy_h<<<cdiv(B_ * H_, 256), 256, 0, stream>>>(h0, X0h[0], H_, H_, 0, B_ * H_);
    copy_h<<<cdiv(B_ * H_, 256), 256, 0, stream>>>(h1, X1[0], H_, K1, H_, B_ * H_);
    copy_h<<<cdiv(B_ * E_, 256), 256, 0, stream>>>(h2, X2[0], E_, K2, H_, B_ * E_);
    copy_f32<<<cdiv(B_ * H_, 256), 256, 0, stream>>>(c0, c0b, B_ * H_);
    copy_f32<<<cdiv(B_ * H_, 256), 256, 0, stream>>>(c1, c1b, B_ * H_);
    copy_f32<<<cdiv(B_ * E_, 256), 256, 0, stream>>>(c2, c2b, B_ * E_);

    // recurrence: 3 fused dispatches per step
    for (int t = 0; t < T_; ++t) {
        int p = t & 1, q = p ^ 1;
        // layer 0: A = [xe(t) | h0(t-1)], K = 1568
        lstm_layer<<<H_ / 16, 256, 0, stream>>>(
            xe + (long)t * B_ * XW, XW, 13,
            X0h[p], H_, 49,
            W0c, K0, b0, H_, c0b,
            X1[p], K1, 0,          // h0 -> layer1 input (this step)
            X0h[q], H_, 0);        // h0 -> layer0 recurrent (next step)
        // layer 1: A = [h0(t) | h1(t-1)], K = 2304
        lstm_layer<<<H_ / 16, 256, 0, stream>>>(
            X1[p], K1, 72,
            X1[p], K1, 72,
            W1c, K1, b1, H_, c1b,
            X2[p], K2, 0,          // h1 -> layer2 input (this step)
            X1[q], K1, H_);        // h1 -> layer1 recurrent (next step)
        // layer 2: A = [h1(t) | h2(t-1) | pad], K = 1568
        lstm_layer<<<E_ / 16, 256, 0, stream>>>(
            X2[p], K2, 49,
            X2[p], K2, 49,
            W2c, K2, b2, E_, c2b,
            X2[q], K2, H_,                     // h2 -> layer2 recurrent (next step)
            outb + (long)t * B_ * XW, XW, 0);  // h2 -> decoder input
    }

    // decoder
    decoder<<<dim3((V_ + 63) / 64, (T_ * B_) / 64), 256, 0, stream>>>(
        outb, Wdc, decb, (float*)d_out);
}

// Round 3
// 20314.766 us; speedup vs baseline: 2.4635x; 2.4635x over previous
//
#include <hip/hip_runtime.h>
#include <hip/hip_bf16.h>
#include <hip/hip_cooperative_groups.h>

namespace cg = cooperative_groups;

typedef __hip_bfloat16 bf16;
typedef __attribute__((ext_vector_type(8))) short short8;
typedef __attribute__((ext_vector_type(4))) float f32x4;

#define T_ 256
#define B_ 64
#define V_ 10000
#define E_ 400
#define H_ 1152

// padded K dims (multiples of 32)
#define K0 1568   // 416 xe(padded) + 1152 h0   (49 k-tiles)
#define K1 2304   // 1152 h0 + 1152 h1          (72 k-tiles)
#define K2 1568   // 1152 h1 + 400 h2 + 16 pad  (49 k-tiles)
#define KD 416    // 400 + 16 pad               (13 k-tiles)
#define XW 416    // padded embedding width

// ---------------- prep kernels ----------------

__global__ __launch_bounds__(256) void prep_wcat(
    const float* __restrict__ s1, int w1,
    const float* __restrict__ s2, int w2, int s2off,
    bf16* __restrict__ dst, int Ktot, long total)
{
    long i = (long)blockIdx.x * 256 + threadIdx.x;
    if (i >= total) return;
    int n = (int)(i / Ktot), k = (int)(i % Ktot);
    float v = 0.f;
    if (k < w1) v = s1[(long)n * w1 + k];
    else if (k >= s2off && k < s2off + w2) v = s2[(long)n * w2 + (k - s2off)];
    dst[i] = __float2bfloat16(v);
}

__global__ __launch_bounds__(256) void bias_add(
    const float* __restrict__ a, const float* __restrict__ b,
    float* __restrict__ d, int n)
{
    int i = blockIdx.x * 256 + threadIdx.x;
    if (i < n) d[i] = a[i] + b[i];
}

__global__ __launch_bounds__(256) void gather_xe(
    const int* __restrict__ x, const float* __restrict__ emb,
    bf16* __restrict__ xe)
{
    long i = (long)blockIdx.x * 256 + threadIdx.x;
    if (i >= (long)T_ * B_ * XW) return;
    int k = (int)(i % XW);
    long tb = i / XW;
    float v = 0.f;
    if (k < E_) v = emb[(long)x[tb] * E_ + k];
    xe[i] = __float2bfloat16(v);
}

__global__ __launch_bounds__(256) void copy_h(
    const float* __restrict__ src, bf16* __restrict__ dst,
    int cols, int dstride, int doff, int total)
{
    int i = blockIdx.x * 256 + threadIdx.x;
    if (i >= total) return;
    int r = i / cols, c = i % cols;
    dst[(long)r * dstride + doff + c] = __float2bfloat16(src[i]);
}

__global__ __launch_bounds__(256) void copy_f32(
    const float* __restrict__ src, float* __restrict__ dst, int n)
{
    int i = blockIdx.x * 256 + threadIdx.x;
    if (i < n) dst[i] = src[i];
}

// ---------------- persistent LSTM ----------------
// One phase = one layer's GEMM+nonlin for a 32-row (batch) half and a 16-col
// hidden strip, all 4 gates (wave g = gate g). A staged in LDS in 512-col
// chunks with XOR swizzle (unit ^ (row&7)) -> conflict-free ds_read_b128.

__device__ __forceinline__ void lstm_phase(
    const bf16* __restrict__ A1, int w1, const bf16* __restrict__ A2, int w2,
    int nkt, const bf16* __restrict__ W, int Kl,
    const float* __restrict__ bias, int Hl,
    float* __restrict__ cbuf,
    bf16* __restrict__ hdst, int hstride,
    bf16* __restrict__ hdst2, int hstride2,
    int strip, int mh,
    char* Achunk, float (*gsm)[32][16])
{
    const int tid = threadIdx.x;
    const int lane = tid & 63;
    const int g = tid >> 6;
    const int j0 = strip * 16;
    const int c16 = lane & 15;
    const int kg = lane >> 4;
    const int K = nkt * 32;

    const bf16* Brow = W + (long)(g * Hl + j0 + c16) * Kl + kg * 8;

    f32x4 acc0 = {0.f, 0.f, 0.f, 0.f}, acc1 = {0.f, 0.f, 0.f, 0.f};

    const int nchunk = (nkt + 15) >> 4;
    for (int kc = 0; kc < nchunk; ++kc) {
        const int ktbase = kc << 4;
        const int cnk = (nkt - ktbase) < 16 ? (nkt - ktbase) : 16;
        __syncthreads();
        // stage 32 rows x (up to) 512 cols of A into LDS, swizzled
        // 32 rows x 64 units(16B) = 2048 units; 256 threads -> 8 iterations
        #pragma unroll
        for (int i = 0; i < 8; ++i) {
            int u = tid + i * 256;
            int row = u >> 6, unit = u & 63;
            int k0 = (ktbase << 5) + unit * 8;
            if (k0 < K) {
                int grow = mh * 32 + row;
                const bf16* src;
                if (k0 < w1) {
                    src = A1 + (long)grow * w1 + k0;
                } else {
                    int k2 = k0 - w1;
                    if (k2 > w2 - 8) k2 = w2 - 8;   // clamp (padding region)
                    src = A2 + (long)grow * w2 + k2;
                }
                short8 v = *(const short8*)src;
                *(short8*)(Achunk + row * 1024 + ((unit ^ (row & 7)) << 4)) = v;
            }
        }
        __syncthreads();

        const bf16* bp = Brow + ((long)ktbase << 5);
        if (cnk == 16) {
            #pragma unroll
            for (int h = 0; h < 2; ++h) {
                short8 bf[8];
                #pragma unroll
                for (int k = 0; k < 8; ++k)
                    bf[k] = *(const short8*)(bp + ((h * 8 + k) << 5));
                #pragma unroll
                for (int k = 0; k < 8; ++k) {
                    int kt = h * 8 + k;
                    int r0 = c16, r1 = 16 + c16;
                    short8 a0 = *(const short8*)(Achunk + r0 * 1024 + ((((kt << 2) + kg) ^ (r0 & 7)) << 4));
                    short8 a1 = *(const short8*)(Achunk + r1 * 1024 + ((((kt << 2) + kg) ^ (r1 & 7)) << 4));
                    acc0 = __builtin_amdgcn_mfma_f32_16x16x32_bf16(a0, bf[k], acc0, 0, 0, 0);
                    acc1 = __builtin_amdgcn_mfma_f32_16x16x32_bf16(a1, bf[k], acc1, 0, 0, 0);
                }
            }
        } else {
            for (int kt = 0; kt < cnk; ++kt) {
                short8 bfr = *(const short8*)(bp + (kt << 5));
                int r0 = c16, r1 = 16 + c16;
                short8 a0 = *(const short8*)(Achunk + r0 * 1024 + ((((kt << 2) + kg) ^ (r0 & 7)) << 4));
                short8 a1 = *(const short8*)(Achunk + r1 * 1024 + ((((kt << 2) + kg) ^ (r1 & 7)) << 4));
                acc0 = __builtin_amdgcn_mfma_f32_16x16x32_bf16(a0, bfr, acc0, 0, 0, 0);
                acc1 = __builtin_amdgcn_mfma_f32_16x16x32_bf16(a1, bfr, acc1, 0, 0, 0);
            }
        }
    }

    float bv = bias[g * Hl + j0 + c16];
    #pragma unroll
    for (int r = 0; r < 4; ++r) {
        gsm[g][kg * 4 + r][c16]      = acc0[r] + bv;
        gsm[g][16 + kg * 4 + r][c16] = acc1[r] + bv;
    }
    __syncthreads();

    #pragma unroll
    for (int i = 0; i < 2; ++i) {
        int idx = tid + i * 256;
        int row = idx >> 4, col = idx & 15;
        float ig = gsm[0][row][col], fg = gsm[1][row][col];
        float gg = gsm[2][row][col], og = gsm[3][row][col];
        int grow = mh * 32 + row;
        long cidx = (long)grow * Hl + j0 + col;
        float c_old = cbuf[cidx];
        float i_s = 1.f / (1.f + expf(-ig));
        float f_s = 1.f / (1.f + expf(-fg));
        float o_s = 1.f / (1.f + expf(-og));
        float c_new = f_s * c_old + i_s * tanhf(gg);
        float hval = o_s * tanhf(c_new);
        cbuf[cidx] = c_new;
        bf16 hb = __float2bfloat16(hval);
        hdst[(long)grow * hstride + j0 + col] = hb;
        if (hdst2) hdst2[(long)grow * hstride2 + j0 + col] = hb;
    }
    // no trailing sync needed: next phase's first __syncthreads orders reuse
}

// grid = 194 WGs x 256 threads, cooperative.
// phase A: L1(t) on WGs 0..143.  phase B: L0(t+1) on WGs 0..143, L2(t) on 144..193.
__global__ __launch_bounds__(256) void awd_persistent(
    const bf16* __restrict__ XE,
    const bf16* __restrict__ W0, const bf16* __restrict__ W1, const bf16* __restrict__ W2,
    const float* __restrict__ b0, const float* __restrict__ b1, const float* __restrict__ b2,
    bf16* H0a, bf16* H0b, bf16* H1a, bf16* H1b, bf16* H2a, bf16* H2b,
    float* c0, float* c1, float* c2, bf16* OUTB)
{
    __shared__ char Achunk[32 * 1024];
    __shared__ float gsm[4][32][16];
    cg::grid_group grid = cg::this_grid();
    const int w = blockIdx.x;

    bf16* H0[2] = {H0a, H0b};
    bf16* H1[2] = {H1a, H1b};
    bf16* H2[2] = {H2a, H2b};

    const int s  = (w < 144) ? (w % 72) : 0;
    const int mh = (w < 144) ? (w / 72) : 0;
    const int s2  = (w >= 144) ? ((w - 144) % 25) : 0;
    const int mh2 = (w >= 144) ? ((w - 144) / 25) : 0;

    // h_l(t) lives in H_l[(t+1)&1]; initial states (t = -1) live in H_l[0].

    // prologue: L0(0) -> H0[1]
    if (w < 144)
        lstm_phase(XE, XW, H0[0], H_, 49, W0, K0, b0, H_, c0,
                   H0[1], H_, nullptr, 0, s, mh, Achunk, gsm);
    grid.sync();

    for (int t = 0; t < T_; ++t) {
        const int p = t & 1, q = p ^ 1;
        // phase A: L1(t): [h0(t) | h1(t-1)] -> h1(t)
        if (w < 144)
            lstm_phase(H0[q], H_, H1[p], H_, 72, W1, K1, b1, H_, c1,
                       H1[q], H_, nullptr, 0, s, mh, Achunk, gsm);
        grid.sync();
        // phase B: L0(t+1) and L2(t)
        if (w < 144) {
            if (t + 1 < T_)
                lstm_phase(XE + (long)(t + 1) * B_ * XW, XW, H0[q], H_, 49, W0, K0, b0, H_, c0,
                           H0[p], H_, nullptr, 0, s, mh, Achunk, gsm);
        } else if (w < 194) {
            lstm_phase(H1[q], H_, H2[p], XW, 49, W2, K2, b2, E_, c2,
                       H2[q], XW, OUTB + (long)t * B_ * XW, XW, s2, mh2, Achunk, gsm);
        }
        grid.sync();
    }
}

// ---------------- decoder GEMM ----------------
__global__ __launch_bounds__(256) void decoder(
    const bf16* __restrict__ A, const bf16* __restrict__ W,
    const float* __restrict__ bias, float* __restrict__ out)
{
    const int tid = threadIdx.x;
    const int lane = tid & 63;
    const int w = tid >> 6;
    const int n0 = blockIdx.x * 64;
    const int m0 = blockIdx.y * 64 + w * 16;
    const int c16 = lane & 15;
    const int kg = lane >> 4;

    f32x4 acc[4];
    for (int i = 0; i < 4; ++i) acc[i] = (f32x4){0.f, 0.f, 0.f, 0.f};

    const bf16* arow = A + (long)(m0 + c16) * KD + kg * 8;
    #pragma unroll
    for (int kt = 0; kt < 13; ++kt) {
        short8 af = *(const short8*)(arow + kt * 32);
        #pragma unroll
        for (int ns = 0; ns < 4; ++ns) {
            int n = n0 + ns * 16 + c16;
            if (n > V_ - 1) n = V_ - 1;
            short8 bfr = *(const short8*)(W + (long)n * KD + kt * 32 + kg * 8);
            acc[ns] = __builtin_amdgcn_mfma_f32_16x16x32_bf16(af, bfr, acc[ns], 0, 0, 0);
        }
    }

    #pragma unroll
    for (int ns = 0; ns < 4; ++ns) {
        int col = n0 + ns * 16 + c16;
        if (col < V_) {
            float bv = bias[col];
            #pragma unroll
            for (int r = 0; r < 4; ++r) {
                int row = m0 + kg * 4 + r;
                out[(size_t)row * V_ + col] = acc[ns][r] + bv;
            }
        }
    }
}

// ---------------- host ----------------

extern "C" void kernel_launch(void* const* d_in, const int* in_sizes, int n_in,
                              void* d_out, int out_size, void* d_ws, size_t ws_size,
                              hipStream_t stream)
{
    const int*   x    = (const int*)d_in[0];
    const float* h0   = (const float*)d_in[1];
    const float* h1   = (const float*)d_in[2];
    const float* h2   = (const float*)d_in[3];
    const float* c0   = (const float*)d_in[4];
    const float* c1   = (const float*)d_in[5];
    const float* c2   = (const float*)d_in[6];
    const float* emb  = (const float*)d_in[7];
    const float* Wih0 = (const float*)d_in[8];
    const float* Whh0 = (const float*)d_in[9];
    const float* bih0 = (const float*)d_in[10];
    const float* bhh0 = (const float*)d_in[11];
    const float* Wih1 = (const float*)d_in[12];
    const float* Whh1 = (const float*)d_in[13];
    const float* bih1 = (const float*)d_in[14];
    const float* bhh1 = (const float*)d_in[15];
    const float* Wih2 = (const float*)d_in[16];
    const float* Whh2 = (const float*)d_in[17];
    const float* bih2 = (const float*)d_in[18];
    const float* bhh2 = (const float*)d_in[19];
    const float* decW = (const float*)d_in[20];
    const float* decb = (const float*)d_in[21];

    char* wsb = (char*)d_ws;
    size_t off = 0;
    auto alloc = [&](size_t bytes) -> void* {
        void* p = wsb + off;
        off = (off + bytes + 255) & ~(size_t)255;
        return p;
    };

    bf16* W0c = (bf16*)alloc((size_t)4 * H_ * K0 * 2);
    bf16* W1c = (bf16*)alloc((size_t)4 * H_ * K1 * 2);
    bf16* W2c = (bf16*)alloc((size_t)4 * E_ * K2 * 2);
    bf16* Wdc = (bf16*)alloc((size_t)V_ * KD * 2);
    float* b0 = (float*)alloc(4 * H_ * 4);
    float* b1 = (float*)alloc(4 * H_ * 4);
    float* b2 = (float*)alloc(4 * E_ * 4);
    bf16* xe  = (bf16*)alloc((size_t)T_ * B_ * XW * 2);
    bf16* H0a = (bf16*)alloc((size_t)B_ * H_ * 2);
    bf16* H0b = (bf16*)alloc((size_t)B_ * H_ * 2);
    bf16* H1a = (bf16*)alloc((size_t)B_ * H_ * 2);
    bf16* H1b = (bf16*)alloc((size_t)B_ * H_ * 2);
    bf16* H2a = (bf16*)alloc((size_t)B_ * XW * 2);
    bf16* H2b = (bf16*)alloc((size_t)B_ * XW * 2);
    float* c0b = (float*)alloc((size_t)B_ * H_ * 4);
    float* c1b = (float*)alloc((size_t)B_ * H_ * 4);
    float* c2b = (float*)alloc((size_t)B_ * E_ * 4);
    bf16* outb = (bf16*)alloc((size_t)T_ * B_ * XW * 2);

    auto cdiv = [](long a, long b) { return (int)((a + b - 1) / b); };

    // weight prep
    prep_wcat<<<cdiv(4608L * K0, 256), 256, 0, stream>>>(Wih0, 400, Whh0, 1152, 416, W0c, K0, 4608L * K0);
    prep_wcat<<<cdiv(4608L * K1, 256), 256, 0, stream>>>(Wih1, 1152, Whh1, 1152, 1152, W1c, K1, 4608L * K1);
    prep_wcat<<<cdiv(1600L * K2, 256), 256, 0, stream>>>(Wih2, 1152, Whh2, 400, 1152, W2c, K2, 1600L * K2);
    prep_wcat<<<cdiv((long)V_ * KD, 256), 256, 0, stream>>>(decW, 400, nullptr, 0, 416, Wdc, KD, (long)V_ * KD);
    bias_add<<<cdiv(4608, 256), 256, 0, stream>>>(bih0, bhh0, b0, 4608);
    bias_add<<<cdiv(4608, 256), 256, 0, stream>>>(bih1, bhh1, b1, 4608);
    bias_add<<<cdiv(1600, 256), 256, 0, stream>>>(bih2, bhh2, b2, 1600);
    gather_xe<<<cdiv((long)T_ * B_ * XW, 256), 256, 0, stream>>>(x, emb, xe);

    // zero padded tails (d_ws is poisoned 0xAA once; re-init every launch)
    hipMemsetAsync(H2a, 0, (size_t)B_ * XW * 2, stream);
    hipMemsetAsync(H2b, 0, (size_t)B_ * XW * 2, stream);
    hipMemsetAsync(outb, 0, (size_t)T_ * B_ * XW * 2, stream);

    // state init
    copy_h<<<cdiv(B_ * H_, 256), 256, 0, stream>>>(h0, H0a, H_, H_, 0, B_ * H_);
    copy_h<<<cdiv(B_ * H_, 256), 256, 0, stream>>>(h1, H1a, H_, H_, 0, B_ * H_);
    copy_h<<<cdiv(B_ * E_, 256), 256, 0, stream>>>(h2, H2a, E_, XW, 0, B_ * E_);
    copy_f32<<<cdiv(B_ * H_, 256), 256, 0, stream>>>(c0, c0b, B_ * H_);
    copy_f32<<<cdiv(B_ * H_, 256), 256, 0, stream>>>(c1, c1b, B_ * H_);
    copy_f32<<<cdiv(B_ * E_, 256), 256, 0, stream>>>(c2, c2b, B_ * E_);

    // persistent recurrence (cooperative: grid-wide sync between phases)
    {
        void* args[] = {
            (void*)&xe, (void*)&W0c, (void*)&W1c, (void*)&W2c,
            (void*)&b0, (void*)&b1, (void*)&b2,
            (void*)&H0a, (void*)&H0b, (void*)&H1a, (void*)&H1b, (void*)&H2a, (void*)&H2b,
            (void*)&c0b, (void*)&c1b, (void*)&c2b, (void*)&outb
        };
        hipLaunchCooperativeKernel((void*)awd_persistent, dim3(194), dim3(256),
                                   args, 0, stream);
    }

    // decoder
    decoder<<<dim3((V_ + 63) / 64, (T_ * B_) / 64), 256, 0, stream>>>(
        outb, Wdc, decb, (float*)d_out);
}

// Round 4
// 10855.519 us; speedup vs baseline: 4.6102x; 1.8714x over previous
//
#include <hip/hip_runtime.h>
#include <hip/hip_bf16.h>
#include <hip/hip_cooperative_groups.h>

namespace cg = cooperative_groups;

typedef __hip_bfloat16 bf16;
typedef __attribute__((ext_vector_type(8))) short short8;
typedef __attribute__((ext_vector_type(4))) float f32x4;

#define T_ 256
#define B_ 64
#define V_ 10000
#define E_ 400
#define H_ 1152
#define KU 2304      // uniform padded K for all layers (72 kt of 32)
#define XW 416       // padded embedding width (13 kt)
#define KD 416       // decoder K (padded)
#define XET (XW*B_)  // 26624 shorts per timestep in frag-major

#define MFMA16 __builtin_amdgcn_mfma_f32_16x16x32_bf16

// ---------------- prep kernels ----------------

// gate-interleaved weight: dst[(hcol*4+gate)][k] over K=2304, zero-padded.
// k<w1 -> Wih[gate*Hl+hcol][k]; off2<=k<off2+w2 -> Whh[gate*Hl+hcol][k-off2]; else 0
__global__ __launch_bounds__(256) void prep_wint(
    const float* __restrict__ s1, int w1,
    const float* __restrict__ s2, int off2, int w2, int Hl,
    bf16* __restrict__ dst, long total)
{
    long i = (long)blockIdx.x * 256 + threadIdx.x;
    if (i >= total) return;
    int r = (int)(i / KU), k = (int)(i % KU);
    int hcol = r >> 2, gate = r & 3;
    long srow = (long)gate * Hl + hcol;
    float v = 0.f;
    if (k < w1) v = s1[srow * w1 + k];
    else if (k >= off2 && k < off2 + w2) v = s2[srow * w2 + (k - off2)];
    dst[i] = __float2bfloat16(v);
}

// decoder weight: plain rows, K padded to 416
__global__ __launch_bounds__(256) void prep_wcat(
    const float* __restrict__ s1, int w1,
    bf16* __restrict__ dst, int Ktot, long total)
{
    long i = (long)blockIdx.x * 256 + threadIdx.x;
    if (i >= total) return;
    int k = (int)(i % Ktot);
    long n = i / Ktot;
    dst[i] = __float2bfloat16(k < w1 ? s1[n * w1 + k] : 0.f);
}

__global__ __launch_bounds__(256) void bias_int(
    const float* __restrict__ a, const float* __restrict__ b,
    int Hl, float* __restrict__ d, int n)
{
    int r = blockIdx.x * 256 + threadIdx.x;
    if (r >= n) return;
    int hcol = r >> 2, gate = r & 3;
    d[r] = a[gate * Hl + hcol] + b[gate * Hl + hcol];
}

// embeddings -> frag-major bf16: XEf[t][(k>>3)*64+b][k&7]
__global__ __launch_bounds__(256) void gather_xef(
    const int* __restrict__ x, const float* __restrict__ emb,
    bf16* __restrict__ XEf)
{
    long i = (long)blockIdx.x * 256 + threadIdx.x;
    if (i >= (long)T_ * B_ * XW) return;
    int k = (int)(i % XW);
    int b = (int)((i / XW) % B_);
    int t = (int)(i / ((long)XW * B_));
    float v = (k < E_) ? emb[(long)x[t * B_ + b] * E_ + k] : 0.f;
    XEf[(long)t * XET + (((k >> 3) * 64 + b) << 3) + (k & 7)] = __float2bfloat16(v);
}

// fp32 [B][cols] -> frag-major bf16
__global__ __launch_bounds__(256) void copy_hf(
    const float* __restrict__ src, bf16* __restrict__ dst, int cols, int total)
{
    int i = blockIdx.x * 256 + threadIdx.x;
    if (i >= total) return;
    int k = i % cols, b = i / cols;
    dst[(((k >> 3) * 64 + b) << 3) + (k & 7)] = __float2bfloat16(src[(long)b * cols + k]);
}

__global__ __launch_bounds__(256) void copy_f32(
    const float* __restrict__ src, float* __restrict__ dst, int n)
{
    int i = blockIdx.x * 256 + threadIdx.x;
    if (i < n) dst[i] = src[i];
}

// ---------------- weight-stationary persistent LSTM ----------------
// 169 WGs: 0..71 -> L1 group, 72..143 -> L0 group, 144..168 -> L2 group.
// Group = 16 h-cols (64 gate-interleaved weight rows), full K (padded 2304).
// Wave (rh, kq): row-half rh (32 rows), K-quarter kq (18 kt). Weights live in
// 144 VGPRs per wave, loaded once. Activations read as B-frags from frag-major
// global buffers. Phase s computes {L0(s+1), L1(s), L2(s-1)}; 1 grid sync each.
__global__ __launch_bounds__(512, 2) void awd_persistent(
    const bf16* __restrict__ XEf,
    const bf16* __restrict__ W0, const bf16* __restrict__ W1, const bf16* __restrict__ W2,
    const float* __restrict__ b0, const float* __restrict__ b1, const float* __restrict__ b2,
    bf16* H0f0, bf16* H0f1, bf16* H1f0, bf16* H1f1, bf16* H2f0, bf16* H2f1,
    float* c0, float* c1, float* c2, bf16* OUTB)
{
    __shared__ float gsm[4][64][65];
    cg::grid_group grid = cg::this_grid();
    const int bid = blockIdx.x;
    const int tid = threadIdx.x;
    const int lane = tid & 63;
    const int w8 = tid >> 6;
    const int rh = w8 & 1, kq = w8 >> 1;
    const int lh = lane >> 4, l15 = lane & 15;
    const int kq18 = kq * 18;
    const int boff8 = (lh * 64 + l15) * 8;

    int layer, grp;
    if (bid < 72)       { layer = 1; grp = bid; }
    else if (bid < 144) { layer = 0; grp = bid - 72; }
    else                { layer = 2; grp = bid - 144; }

    const bf16* Wp  = (layer == 0) ? W0 : (layer == 1) ? W1 : W2;
    const float* bias = (layer == 0) ? b0 : (layer == 1) ? b1 : b2;
    float* cbuf = (layer == 0) ? c0 : (layer == 1) ? c1 : c2;
    const int Hl  = (layer == 2) ? 400 : 1152;
    const int bkt = (layer == 0) ? 13 : 36;   // kt where A switches from A1 to A2
    const int nkt = (layer == 1) ? 72 : 49;   // real kt count

    // ---- load weights into registers (once) ----
    short8 wreg[18][2];
    #pragma unroll
    for (int u = 0; u < 18; ++u)
        #pragma unroll
        for (int rt = 0; rt < 2; ++rt) {
            int row = grp * 64 + rh * 32 + rt * 16 + l15;
            int k   = (kq18 + u) * 32 + lh * 8;
            wreg[u][rt] = *(const short8*)(Wp + (long)row * KU + k);
        }

    float myb[2][4];
    #pragma unroll
    for (int e = 0; e < 2; ++e)
        #pragma unroll
        for (int g = 0; g < 4; ++g)
            myb[e][g] = bias[grp * 64 + (w8 + e * 8) * 4 + g];

    for (int s = -1; s <= 256; ++s) {
        bool active = (layer == 0) ? (s <= 254)
                    : (layer == 1) ? (s >= 0 && s <= 255)
                                   : (s >= 1);
        if (active) {
            const int p = s & 1, q = p ^ 1;
            const bf16 *A1, *A2; bf16* hfW; bf16* ob = nullptr;
            if (layer == 0) {
                A1 = XEf + (long)(s + 1) * XET;
                A2 = p ? H0f1 : H0f0;
                hfW = q ? H0f1 : H0f0;
            } else if (layer == 1) {
                A1 = p ? H0f1 : H0f0;
                A2 = q ? H1f1 : H1f0;
                hfW = p ? H1f1 : H1f0;
            } else {
                A1 = q ? H1f1 : H1f0;
                A2 = p ? H2f1 : H2f0;
                hfW = q ? H2f1 : H2f0;
                ob = OUTB + (long)(s - 1) * B_ * XW;
            }

            f32x4 acc[2][4];
            #pragma unroll
            for (int rt = 0; rt < 2; ++rt)
                #pragma unroll
                for (int m = 0; m < 4; ++m)
                    acc[rt][m] = (f32x4){0.f, 0.f, 0.f, 0.f};

            #pragma unroll
            for (int u = 0; u < 18; ++u) {
                const int ktg = kq18 + u;
                const bf16* src; int ktL;
                if (ktg < bkt)      { src = A1; ktL = ktg; }
                else if (ktg < nkt) { src = A2; ktL = ktg - bkt; }
                else                { src = A1; ktL = 0; }   // pad: zero weights
                const bf16* pB = src + ktL * 2048 + boff8;
                short8 bf0 = *(const short8*)(pB);
                short8 bf1 = *(const short8*)(pB + 128);
                short8 bf2 = *(const short8*)(pB + 256);
                short8 bf3 = *(const short8*)(pB + 384);
                acc[0][0] = MFMA16(wreg[u][0], bf0, acc[0][0], 0, 0, 0);
                acc[1][0] = MFMA16(wreg[u][1], bf0, acc[1][0], 0, 0, 0);
                acc[0][1] = MFMA16(wreg[u][0], bf1, acc[0][1], 0, 0, 0);
                acc[1][1] = MFMA16(wreg[u][1], bf1, acc[1][1], 0, 0, 0);
                acc[0][2] = MFMA16(wreg[u][0], bf2, acc[0][2], 0, 0, 0);
                acc[1][2] = MFMA16(wreg[u][1], bf2, acc[1][2], 0, 0, 0);
                acc[0][3] = MFMA16(wreg[u][0], bf3, acc[0][3], 0, 0, 0);
                acc[1][3] = MFMA16(wreg[u][1], bf3, acc[1][3], 0, 0, 0);
            }

            __syncthreads();   // protect previous phase's gsm reads
            #pragma unroll
            for (int rt = 0; rt < 2; ++rt)
                #pragma unroll
                for (int m = 0; m < 4; ++m)
                    #pragma unroll
                    for (int r = 0; r < 4; ++r)
                        gsm[kq][rh * 32 + rt * 16 + lh * 4 + r][m * 16 + l15] = acc[rt][m][r];
            __syncthreads();

            // nonlinearity: 1024 outputs (16 cols x 64 batch), 2 per thread
            #pragma unroll
            for (int e = 0; e < 2; ++e) {
                int b = lane;
                int cl = w8 + e * 8;
                float gv[4];
                #pragma unroll
                for (int g = 0; g < 4; ++g)
                    gv[g] = gsm[0][cl * 4 + g][b] + gsm[1][cl * 4 + g][b]
                          + gsm[2][cl * 4 + g][b] + gsm[3][cl * 4 + g][b] + myb[e][g];
                int colG = grp * 16 + cl;
                long cidx = (long)b * Hl + colG;
                float c_old = cbuf[cidx];
                float i_s = 1.f / (1.f + expf(-gv[0]));
                float f_s = 1.f / (1.f + expf(-gv[1]));
                float o_s = 1.f / (1.f + expf(-gv[3]));
                float c_new = f_s * c_old + i_s * tanhf(gv[2]);
                float hval = o_s * tanhf(c_new);
                cbuf[cidx] = c_new;
                bf16 hb = __float2bfloat16(hval);
                hfW[(((colG >> 3) * 64 + b) << 3) + (colG & 7)] = hb;
                if (layer == 2) ob[(long)b * XW + colG] = hb;
            }
        }
        grid.sync();
    }
}

// ---------------- decoder GEMM ----------------
__global__ __launch_bounds__(256) void decoder(
    const bf16* __restrict__ A, const bf16* __restrict__ W,
    const float* __restrict__ bias, float* __restrict__ out)
{
    const int tid = threadIdx.x;
    const int lane = tid & 63;
    const int w = tid >> 6;
    const int n0 = blockIdx.x * 64;
    const int m0 = blockIdx.y * 64 + w * 16;
    const int c16 = lane & 15;
    const int kg = lane >> 4;

    f32x4 acc[4];
    for (int i = 0; i < 4; ++i) acc[i] = (f32x4){0.f, 0.f, 0.f, 0.f};

    const bf16* arow = A + (long)(m0 + c16) * KD + kg * 8;
    #pragma unroll
    for (int kt = 0; kt < 13; ++kt) {
        short8 af = *(const short8*)(arow + kt * 32);
        #pragma unroll
        for (int ns = 0; ns < 4; ++ns) {
            int n = n0 + ns * 16 + c16;
            if (n > V_ - 1) n = V_ - 1;
            short8 bfr = *(const short8*)(W + (long)n * KD + kt * 32 + kg * 8);
            acc[ns] = MFMA16(af, bfr, acc[ns], 0, 0, 0);
        }
    }

    #pragma unroll
    for (int ns = 0; ns < 4; ++ns) {
        int col = n0 + ns * 16 + c16;
        if (col < V_) {
            float bv = bias[col];
            #pragma unroll
            for (int r = 0; r < 4; ++r) {
                int row = m0 + kg * 4 + r;
                out[(size_t)row * V_ + col] = acc[ns][r] + bv;
            }
        }
    }
}

// ---------------- host ----------------

extern "C" void kernel_launch(void* const* d_in, const int* in_sizes, int n_in,
                              void* d_out, int out_size, void* d_ws, size_t ws_size,
                              hipStream_t stream)
{
    const int*   x    = (const int*)d_in[0];
    const float* h0   = (const float*)d_in[1];
    const float* h1   = (const float*)d_in[2];
    const float* h2   = (const float*)d_in[3];
    const float* c0   = (const float*)d_in[4];
    const float* c1   = (const float*)d_in[5];
    const float* c2   = (const float*)d_in[6];
    const float* emb  = (const float*)d_in[7];
    const float* Wih0 = (const float*)d_in[8];
    const float* Whh0 = (const float*)d_in[9];
    const float* bih0 = (const float*)d_in[10];
    const float* bhh0 = (const float*)d_in[11];
    const float* Wih1 = (const float*)d_in[12];
    const float* Whh1 = (const float*)d_in[13];
    const float* bih1 = (const float*)d_in[14];
    const float* bhh1 = (const float*)d_in[15];
    const float* Wih2 = (const float*)d_in[16];
    const float* Whh2 = (const float*)d_in[17];
    const float* bih2 = (const float*)d_in[18];
    const float* bhh2 = (const float*)d_in[19];
    const float* decW = (const float*)d_in[20];
    const float* decb = (const float*)d_in[21];

    char* wsb = (char*)d_ws;
    size_t off = 0;
    auto alloc = [&](size_t bytes) -> void* {
        void* ptr = wsb + off;
        off = (off + bytes + 255) & ~(size_t)255;
        return ptr;
    };

    bf16* W0i = (bf16*)alloc((size_t)4608 * KU * 2);
    bf16* W1i = (bf16*)alloc((size_t)4608 * KU * 2);
    bf16* W2i = (bf16*)alloc((size_t)1600 * KU * 2);
    bf16* Wdc = (bf16*)alloc((size_t)V_ * KD * 2);
    float* b0i = (float*)alloc(4608 * 4);
    float* b1i = (float*)alloc(4608 * 4);
    float* b2i = (float*)alloc(1600 * 4);
    bf16* XEf = (bf16*)alloc((size_t)T_ * XET * 2);
    bf16* H0f0 = (bf16*)alloc((size_t)B_ * H_ * 2);
    bf16* H0f1 = (bf16*)alloc((size_t)B_ * H_ * 2);
    bf16* H1f0 = (bf16*)alloc((size_t)B_ * H_ * 2);
    bf16* H1f1 = (bf16*)alloc((size_t)B_ * H_ * 2);
    bf16* H2f0 = (bf16*)alloc((size_t)B_ * XW * 2);
    bf16* H2f1 = (bf16*)alloc((size_t)B_ * XW * 2);
    float* c0b = (float*)alloc((size_t)B_ * H_ * 4);
    float* c1b = (float*)alloc((size_t)B_ * H_ * 4);
    float* c2b = (float*)alloc((size_t)B_ * E_ * 4);
    bf16* OUTB = (bf16*)alloc((size_t)T_ * B_ * XW * 2);

    auto cdiv = [](long a, long b) { return (int)((a + b - 1) / b); };

    // weight prep (gate-interleaved, K padded to 2304)
    prep_wint<<<cdiv(4608L * KU, 256), 256, 0, stream>>>(Wih0, 400,  Whh0, 416,  1152, 1152, W0i, 4608L * KU);
    prep_wint<<<cdiv(4608L * KU, 256), 256, 0, stream>>>(Wih1, 1152, Whh1, 1152, 1152, 1152, W1i, 4608L * KU);
    prep_wint<<<cdiv(1600L * KU, 256), 256, 0, stream>>>(Wih2, 1152, Whh2, 1152, 400,  400,  W2i, 1600L * KU);
    prep_wcat<<<cdiv((long)V_ * KD, 256), 256, 0, stream>>>(decW, 400, Wdc, KD, (long)V_ * KD);
    bias_int<<<cdiv(4608, 256), 256, 0, stream>>>(bih0, bhh0, 1152, b0i, 4608);
    bias_int<<<cdiv(4608, 256), 256, 0, stream>>>(bih1, bhh1, 1152, b1i, 4608);
    bias_int<<<cdiv(1600, 256), 256, 0, stream>>>(bih2, bhh2, 400,  b2i, 1600);
    gather_xef<<<cdiv((long)T_ * B_ * XW, 256), 256, 0, stream>>>(x, emb, XEf);

    // zero pads (h2 frag buffers have cols 400..415 never written; OUTB pads feed decoder)
    hipMemsetAsync(H2f0, 0, (size_t)B_ * XW * 2, stream);
    hipMemsetAsync(H2f1, 0, (size_t)B_ * XW * 2, stream);
    hipMemsetAsync(OUTB, 0, (size_t)T_ * B_ * XW * 2, stream);

    // initial states: h -> frag-major parity-1 buffers, c -> fp32 plain
    copy_hf<<<cdiv(B_ * H_, 256), 256, 0, stream>>>(h0, H0f1, H_, B_ * H_);
    copy_hf<<<cdiv(B_ * H_, 256), 256, 0, stream>>>(h1, H1f1, H_, B_ * H_);
    copy_hf<<<cdiv(B_ * E_, 256), 256, 0, stream>>>(h2, H2f1, E_, B_ * E_);
    copy_f32<<<cdiv(B_ * H_, 256), 256, 0, stream>>>(c0, c0b, B_ * H_);
    copy_f32<<<cdiv(B_ * H_, 256), 256, 0, stream>>>(c1, c1b, B_ * H_);
    copy_f32<<<cdiv(B_ * E_, 256), 256, 0, stream>>>(c2, c2b, B_ * E_);

    // persistent weight-stationary recurrence
    {
        void* args[] = {
            (void*)&XEf, (void*)&W0i, (void*)&W1i, (void*)&W2i,
            (void*)&b0i, (void*)&b1i, (void*)&b2i,
            (void*)&H0f0, (void*)&H0f1, (void*)&H1f0, (void*)&H1f1,
            (void*)&H2f0, (void*)&H2f1,
            (void*)&c0b, (void*)&c1b, (void*)&c2b, (void*)&OUTB
        };
        hipLaunchCooperativeKernel((void*)awd_persistent, dim3(169), dim3(512),
                                   args, 0, stream);
    }

    // decoder
    decoder<<<dim3((V_ + 63) / 64, (T_ * B_) / 64), 256, 0, stream>>>(
        OUTB, Wdc, decb, (float*)d_out);
}

// Round 5
// 6755.280 us; speedup vs baseline: 7.4084x; 1.6070x over previous
//
#include <hip/hip_runtime.h>
#include <hip/hip_bf16.h>
#include <hip/hip_cooperative_groups.h>

namespace cg = cooperative_groups;

typedef __hip_bfloat16 bf16;
typedef __attribute__((ext_vector_type(8))) short short8;
typedef __attribute__((ext_vector_type(4))) float f32x4;

#define T_ 256
#define B_ 64
#define V_ 10000
#define E_ 400
#define H_ 1152
#define KU 2304      // uniform padded K for all layers (72 kt of 32)
#define XW 416       // padded embedding width (13 kt)
#define KD 416       // decoder K (padded)
#define XET (XW*B_)  // 26624 shorts per timestep in frag-major
#define NBLK 169

#define MFMA16 __builtin_amdgcn_mfma_f32_16x16x32_bf16

// ---------------- prep kernels ----------------

// gate-interleaved weight: dst[(hcol*4+gate)][k] over K=2304, zero-padded.
__global__ __launch_bounds__(256) void prep_wint(
    const float* __restrict__ s1, int w1,
    const float* __restrict__ s2, int off2, int w2, int Hl,
    bf16* __restrict__ dst, long total)
{
    long i = (long)blockIdx.x * 256 + threadIdx.x;
    if (i >= total) return;
    int r = (int)(i / KU), k = (int)(i % KU);
    int hcol = r >> 2, gate = r & 3;
    long srow = (long)gate * Hl + hcol;
    float v = 0.f;
    if (k < w1) v = s1[srow * w1 + k];
    else if (k >= off2 && k < off2 + w2) v = s2[srow * w2 + (k - off2)];
    dst[i] = __float2bfloat16(v);
}

// decoder weight: plain rows, K padded to 416
__global__ __launch_bounds__(256) void prep_wcat(
    const float* __restrict__ s1, int w1,
    bf16* __restrict__ dst, int Ktot, long total)
{
    long i = (long)blockIdx.x * 256 + threadIdx.x;
    if (i >= total) return;
    int k = (int)(i % Ktot);
    long n = i / Ktot;
    dst[i] = __float2bfloat16(k < w1 ? s1[n * w1 + k] : 0.f);
}

__global__ __launch_bounds__(256) void bias_int(
    const float* __restrict__ a, const float* __restrict__ b,
    int Hl, float* __restrict__ d, int n)
{
    int r = blockIdx.x * 256 + threadIdx.x;
    if (r >= n) return;
    int hcol = r >> 2, gate = r & 3;
    d[r] = a[gate * Hl + hcol] + b[gate * Hl + hcol];
}

// embeddings -> frag-major bf16: XEf[t][(k>>3)*64+b][k&7]
__global__ __launch_bounds__(256) void gather_xef(
    const int* __restrict__ x, const float* __restrict__ emb,
    bf16* __restrict__ XEf)
{
    long i = (long)blockIdx.x * 256 + threadIdx.x;
    if (i >= (long)T_ * B_ * XW) return;
    int k = (int)(i % XW);
    int b = (int)((i / XW) % B_);
    int t = (int)(i / ((long)XW * B_));
    float v = (k < E_) ? emb[(long)x[t * B_ + b] * E_ + k] : 0.f;
    XEf[(long)t * XET + (((k >> 3) * 64 + b) << 3) + (k & 7)] = __float2bfloat16(v);
}

// fp32 [B][cols] -> frag-major bf16
__global__ __launch_bounds__(256) void copy_hf(
    const float* __restrict__ src, bf16* __restrict__ dst, int cols, int total)
{
    int i = blockIdx.x * 256 + threadIdx.x;
    if (i >= total) return;
    int k = i % cols, b = i / cols;
    dst[(((k >> 3) * 64 + b) << 3) + (k & 7)] = __float2bfloat16(src[(long)b * cols + k]);
}

__global__ __launch_bounds__(256) void copy_f32(
    const float* __restrict__ src, float* __restrict__ dst, int n)
{
    int i = blockIdx.x * 256 + threadIdx.x;
    if (i < n) dst[i] = src[i];
}

// ---------------- lightweight grid barrier ----------------
// Generation barrier, agent scope (cross-XCD release/acquire). tid 0 arrives;
// last arriver resets cnt and bumps gen (release); others spin relaxed then
// acquire. Replaces cg::grid_group::sync() (~39 us measured R3/R4).
__device__ __forceinline__ void grid_bar(int* cnt, int* gen) {
    __syncthreads();
    if (threadIdx.x == 0) {
        int g = __hip_atomic_load(gen, __ATOMIC_RELAXED, __HIP_MEMORY_SCOPE_AGENT);
        int a = __hip_atomic_fetch_add(cnt, 1, __ATOMIC_ACQ_REL, __HIP_MEMORY_SCOPE_AGENT);
        if (a == NBLK - 1) {
            __hip_atomic_store(cnt, 0, __ATOMIC_RELAXED, __HIP_MEMORY_SCOPE_AGENT);
            __hip_atomic_store(gen, g + 1, __ATOMIC_RELEASE, __HIP_MEMORY_SCOPE_AGENT);
        } else {
            while (__hip_atomic_load(gen, __ATOMIC_RELAXED, __HIP_MEMORY_SCOPE_AGENT) == g)
                __builtin_amdgcn_s_sleep(1);
            (void)__hip_atomic_load(gen, __ATOMIC_ACQUIRE, __HIP_MEMORY_SCOPE_AGENT);
        }
    }
    __syncthreads();
}

// ---------------- weight-stationary persistent LSTM ----------------
// 169 WGs: 0..71 -> L1 group, 72..143 -> L0 group, 144..168 -> L2 group.
// Weights register-resident; activations frag-major in global; 1 barrier/step.
__global__ __launch_bounds__(512, 2) void awd_persistent(
    const bf16* __restrict__ XEf,
    const bf16* __restrict__ W0, const bf16* __restrict__ W1, const bf16* __restrict__ W2,
    const float* __restrict__ b0, const float* __restrict__ b1, const float* __restrict__ b2,
    bf16* H0f0, bf16* H0f1, bf16* H1f0, bf16* H1f1, bf16* H2f0, bf16* H2f1,
    float* c0, float* c1, float* c2, bf16* OUTB,
    int* bcnt, int* bgen)
{
    __shared__ float gsm[4][64][65];
    const int bid = blockIdx.x;
    const int tid = threadIdx.x;
    const int lane = tid & 63;
    const int w8 = tid >> 6;
    const int rh = w8 & 1, kq = w8 >> 1;
    const int lh = lane >> 4, l15 = lane & 15;
    const int kq18 = kq * 18;
    const int boff8 = (lh * 64 + l15) * 8;

    int layer, grp;
    if (bid < 72)       { layer = 1; grp = bid; }
    else if (bid < 144) { layer = 0; grp = bid - 72; }
    else                { layer = 2; grp = bid - 144; }

    const bf16* Wp  = (layer == 0) ? W0 : (layer == 1) ? W1 : W2;
    const float* bias = (layer == 0) ? b0 : (layer == 1) ? b1 : b2;
    float* cbuf = (layer == 0) ? c0 : (layer == 1) ? c1 : c2;
    const int Hl  = (layer == 2) ? 400 : 1152;
    const int bkt = (layer == 0) ? 13 : 36;   // kt where A switches from A1 to A2
    const int nkt = (layer == 1) ? 72 : 49;   // real kt count

    // ---- load weights into registers (once) ----
    short8 wreg[18][2];
    #pragma unroll
    for (int u = 0; u < 18; ++u)
        #pragma unroll
        for (int rt = 0; rt < 2; ++rt) {
            int row = grp * 64 + rh * 32 + rt * 16 + l15;
            int k   = (kq18 + u) * 32 + lh * 8;
            wreg[u][rt] = *(const short8*)(Wp + (long)row * KU + k);
        }

    float myb[2][4];
    #pragma unroll
    for (int e = 0; e < 2; ++e)
        #pragma unroll
        for (int g = 0; g < 4; ++g)
            myb[e][g] = bias[grp * 64 + (w8 + e * 8) * 4 + g];

    for (int s = -1; s <= 256; ++s) {
        bool active = (layer == 0) ? (s <= 254)
                    : (layer == 1) ? (s >= 0 && s <= 255)
                                   : (s >= 1);
        if (active) {
            const int p = s & 1, q = p ^ 1;
            const bf16 *A1, *A2; bf16* hfW; bf16* ob = nullptr;
            if (layer == 0) {
                A1 = XEf + (long)(s + 1) * XET;
                A2 = p ? H0f1 : H0f0;
                hfW = q ? H0f1 : H0f0;
            } else if (layer == 1) {
                A1 = p ? H0f1 : H0f0;
                A2 = q ? H1f1 : H1f0;
                hfW = p ? H1f1 : H1f0;
            } else {
                A1 = q ? H1f1 : H1f0;
                A2 = p ? H2f1 : H2f0;
                hfW = q ? H2f1 : H2f0;
                ob = OUTB + (long)(s - 1) * B_ * XW;
            }

            f32x4 acc[2][4];
            #pragma unroll
            for (int rt = 0; rt < 2; ++rt)
                #pragma unroll
                for (int m = 0; m < 4; ++m)
                    acc[rt][m] = (f32x4){0.f, 0.f, 0.f, 0.f};

            #pragma unroll
            for (int u = 0; u < 18; ++u) {
                const int ktg = kq18 + u;
                const bf16* src; int ktL;
                if (ktg < bkt)      { src = A1; ktL = ktg; }
                else if (ktg < nkt) { src = A2; ktL = ktg - bkt; }
                else                { src = A1; ktL = 0; }   // pad: zero weights
                const bf16* pB = src + ktL * 2048 + boff8;
                short8 bf0 = *(const short8*)(pB);
                short8 bf1 = *(const short8*)(pB + 128);
                short8 bf2 = *(const short8*)(pB + 256);
                short8 bf3 = *(const short8*)(pB + 384);
                acc[0][0] = MFMA16(wreg[u][0], bf0, acc[0][0], 0, 0, 0);
                acc[1][0] = MFMA16(wreg[u][1], bf0, acc[1][0], 0, 0, 0);
                acc[0][1] = MFMA16(wreg[u][0], bf1, acc[0][1], 0, 0, 0);
                acc[1][1] = MFMA16(wreg[u][1], bf1, acc[1][1], 0, 0, 0);
                acc[0][2] = MFMA16(wreg[u][0], bf2, acc[0][2], 0, 0, 0);
                acc[1][2] = MFMA16(wreg[u][1], bf2, acc[1][2], 0, 0, 0);
                acc[0][3] = MFMA16(wreg[u][0], bf3, acc[0][3], 0, 0, 0);
                acc[1][3] = MFMA16(wreg[u][1], bf3, acc[1][3], 0, 0, 0);
            }

            __syncthreads();   // protect previous phase's gsm reads
            #pragma unroll
            for (int rt = 0; rt < 2; ++rt)
                #pragma unroll
                for (int m = 0; m < 4; ++m)
                    #pragma unroll
                    for (int r = 0; r < 4; ++r)
                        gsm[kq][rh * 32 + rt * 16 + lh * 4 + r][m * 16 + l15] = acc[rt][m][r];
            __syncthreads();

            // nonlinearity: 1024 outputs (16 cols x 64 batch), 2 per thread
            #pragma unroll
            for (int e = 0; e < 2; ++e) {
                int b = lane;
                int cl = w8 + e * 8;
                float gv[4];
                #pragma unroll
                for (int g = 0; g < 4; ++g)
                    gv[g] = gsm[0][cl * 4 + g][b] + gsm[1][cl * 4 + g][b]
                          + gsm[2][cl * 4 + g][b] + gsm[3][cl * 4 + g][b] + myb[e][g];
                int colG = grp * 16 + cl;
                long cidx = (long)b * Hl + colG;
                float c_old = cbuf[cidx];
                float i_s = 1.f / (1.f + expf(-gv[0]));
                float f_s = 1.f / (1.f + expf(-gv[1]));
                float o_s = 1.f / (1.f + expf(-gv[3]));
                float c_new = f_s * c_old + i_s * tanhf(gv[2]);
                float hval = o_s * tanhf(c_new);
                cbuf[cidx] = c_new;
                bf16 hb = __float2bfloat16(hval);
                hfW[(((colG >> 3) * 64 + b) << 3) + (colG & 7)] = hb;
                if (layer == 2) ob[(long)b * XW + colG] = hb;
            }
        }
        grid_bar(bcnt, bgen);
    }
}

// ---------------- decoder GEMM ----------------
__global__ __launch_bounds__(256) void decoder(
    const bf16* __restrict__ A, const bf16* __restrict__ W,
    const float* __restrict__ bias, float* __restrict__ out)
{
    const int tid = threadIdx.x;
    const int lane = tid & 63;
    const int w = tid >> 6;
    const int n0 = blockIdx.x * 64;
    const int m0 = blockIdx.y * 64 + w * 16;
    const int c16 = lane & 15;
    const int kg = lane >> 4;

    f32x4 acc[4];
    for (int i = 0; i < 4; ++i) acc[i] = (f32x4){0.f, 0.f, 0.f, 0.f};

    const bf16* arow = A + (long)(m0 + c16) * KD + kg * 8;
    #pragma unroll
    for (int kt = 0; kt < 13; ++kt) {
        short8 af = *(const short8*)(arow + kt * 32);
        #pragma unroll
        for (int ns = 0; ns < 4; ++ns) {
            int n = n0 + ns * 16 + c16;
            if (n > V_ - 1) n = V_ - 1;
            short8 bfr = *(const short8*)(W + (long)n * KD + kt * 32 + kg * 8);
            acc[ns] = MFMA16(af, bfr, acc[ns], 0, 0, 0);
        }
    }

    #pragma unroll
    for (int ns = 0; ns < 4; ++ns) {
        int col = n0 + ns * 16 + c16;
        if (col < V_) {
            float bv = bias[col];
            #pragma unroll
            for (int r = 0; r < 4; ++r) {
                int row = m0 + kg * 4 + r;
                out[(size_t)row * V_ + col] = acc[ns][r] + bv;
            }
        }
    }
}

// ---------------- host ----------------

extern "C" void kernel_launch(void* const* d_in, const int* in_sizes, int n_in,
                              void* d_out, int out_size, void* d_ws, size_t ws_size,
                              hipStream_t stream)
{
    const int*   x    = (const int*)d_in[0];
    const float* h0   = (const float*)d_in[1];
    const float* h1   = (const float*)d_in[2];
    const float* h2   = (const float*)d_in[3];
    const float* c0   = (const float*)d_in[4];
    const float* c1   = (const float*)d_in[5];
    const float* c2   = (const float*)d_in[6];
    const float* emb  = (const float*)d_in[7];
    const float* Wih0 = (const float*)d_in[8];
    const float* Whh0 = (const float*)d_in[9];
    const float* bih0 = (const float*)d_in[10];
    const float* bhh0 = (const float*)d_in[11];
    const float* Wih1 = (const float*)d_in[12];
    const float* Whh1 = (const float*)d_in[13];
    const float* bih1 = (const float*)d_in[14];
    const float* bhh1 = (const float*)d_in[15];
    const float* Wih2 = (const float*)d_in[16];
    const float* Whh2 = (const float*)d_in[17];
    const float* bih2 = (const float*)d_in[18];
    const float* bhh2 = (const float*)d_in[19];
    const float* decW = (const float*)d_in[20];
    const float* decb = (const float*)d_in[21];

    char* wsb = (char*)d_ws;
    size_t off = 0;
    auto alloc = [&](size_t bytes) -> void* {
        void* ptr = wsb + off;
        off = (off + bytes + 255) & ~(size_t)255;
        return ptr;
    };

    bf16* W0i = (bf16*)alloc((size_t)4608 * KU * 2);
    bf16* W1i = (bf16*)alloc((size_t)4608 * KU * 2);
    bf16* W2i = (bf16*)alloc((size_t)1600 * KU * 2);
    bf16* Wdc = (bf16*)alloc((size_t)V_ * KD * 2);
    float* b0i = (float*)alloc(4608 * 4);
    float* b1i = (float*)alloc(4608 * 4);
    float* b2i = (float*)alloc(1600 * 4);
    bf16* XEf = (bf16*)alloc((size_t)T_ * XET * 2);
    bf16* H0f0 = (bf16*)alloc((size_t)B_ * H_ * 2);
    bf16* H0f1 = (bf16*)alloc((size_t)B_ * H_ * 2);
    bf16* H1f0 = (bf16*)alloc((size_t)B_ * H_ * 2);
    bf16* H1f1 = (bf16*)alloc((size_t)B_ * H_ * 2);
    bf16* H2f0 = (bf16*)alloc((size_t)B_ * XW * 2);
    bf16* H2f1 = (bf16*)alloc((size_t)B_ * XW * 2);
    float* c0b = (float*)alloc((size_t)B_ * H_ * 4);
    float* c1b = (float*)alloc((size_t)B_ * H_ * 4);
    float* c2b = (float*)alloc((size_t)B_ * E_ * 4);
    bf16* OUTB = (bf16*)alloc((size_t)T_ * B_ * XW * 2);
    int* gbar = (int*)alloc(256);   // [0]=cnt, [32]=gen (128 B apart)

    auto cdiv = [](long a, long b) { return (int)((a + b - 1) / b); };

    // barrier re-init every launch (ws is poisoned once before timing)
    hipMemsetAsync(gbar, 0, 256, stream);

    // weight prep (gate-interleaved, K padded to 2304)
    prep_wint<<<cdiv(4608L * KU, 256), 256, 0, stream>>>(Wih0, 400,  Whh0, 416,  1152, 1152, W0i, 4608L * KU);
    prep_wint<<<cdiv(4608L * KU, 256), 256, 0, stream>>>(Wih1, 1152, Whh1, 1152, 1152, 1152, W1i, 4608L * KU);
    prep_wint<<<cdiv(1600L * KU, 256), 256, 0, stream>>>(Wih2, 1152, Whh2, 1152, 400,  400,  W2i, 1600L * KU);
    prep_wcat<<<cdiv((long)V_ * KD, 256), 256, 0, stream>>>(decW, 400, Wdc, KD, (long)V_ * KD);
    bias_int<<<cdiv(4608, 256), 256, 0, stream>>>(bih0, bhh0, 1152, b0i, 4608);
    bias_int<<<cdiv(4608, 256), 256, 0, stream>>>(bih1, bhh1, 1152, b1i, 4608);
    bias_int<<<cdiv(1600, 256), 256, 0, stream>>>(bih2, bhh2, 400,  b2i, 1600);
    gather_xef<<<cdiv((long)T_ * B_ * XW, 256), 256, 0, stream>>>(x, emb, XEf);

    // zero pads (h2 frag buffers have cols 400..415 never written; OUTB pads feed decoder)
    hipMemsetAsync(H2f0, 0, (size_t)B_ * XW * 2, stream);
    hipMemsetAsync(H2f1, 0, (size_t)B_ * XW * 2, stream);
    hipMemsetAsync(OUTB, 0, (size_t)T_ * B_ * XW * 2, stream);

    // initial states: h -> frag-major parity-1 buffers, c -> fp32 plain
    copy_hf<<<cdiv(B_ * H_, 256), 256, 0, stream>>>(h0, H0f1, H_, B_ * H_);
    copy_hf<<<cdiv(B_ * H_, 256), 256, 0, stream>>>(h1, H1f1, H_, B_ * H_);
    copy_hf<<<cdiv(B_ * E_, 256), 256, 0, stream>>>(h2, H2f1, E_, B_ * E_);
    copy_f32<<<cdiv(B_ * H_, 256), 256, 0, stream>>>(c0, c0b, B_ * H_);
    copy_f32<<<cdiv(B_ * H_, 256), 256, 0, stream>>>(c1, c1b, B_ * H_);
    copy_f32<<<cdiv(B_ * E_, 256), 256, 0, stream>>>(c2, c2b, B_ * E_);

    // persistent weight-stationary recurrence
    {
        void* args[] = {
            (void*)&XEf, (void*)&W0i, (void*)&W1i, (void*)&W2i,
            (void*)&b0i, (void*)&b1i, (void*)&b2i,
            (void*)&H0f0, (void*)&H0f1, (void*)&H1f0, (void*)&H1f1,
            (void*)&H2f0, (void*)&H2f1,
            (void*)&c0b, (void*)&c1b, (void*)&c2b, (void*)&OUTB,
            (void*)&gbar
        };
        int* bcnt = gbar;
        int* bgen = gbar + 32;
        void* args2[] = {
            (void*)&XEf, (void*)&W0i, (void*)&W1i, (void*)&W2i,
            (void*)&b0i, (void*)&b1i, (void*)&b2i,
            (void*)&H0f0, (void*)&H0f1, (void*)&H1f0, (void*)&H1f1,
            (void*)&H2f0, (void*)&H2f1,
            (void*)&c0b, (void*)&c1b, (void*)&c2b, (void*)&OUTB,
            (void*)&bcnt, (void*)&bgen
        };
        (void)args;
        hipLaunchCooperativeKernel((void*)awd_persistent, dim3(NBLK), dim3(512),
                                   args2, 0, stream);
    }

    // decoder
    decoder<<<dim3((V_ + 63) / 64, (T_ * B_) / 64), 256, 0, stream>>>(
        OUTB, Wdc, decb, (float*)d_out);
}

// Round 6
// 5775.710 us; speedup vs baseline: 8.6649x; 1.1696x over previous
//
#include <hip/hip_runtime.h>
#include <hip/hip_bf16.h>

typedef __hip_bfloat16 bf16;
typedef __attribute__((ext_vector_type(8))) short short8;
typedef __attribute__((ext_vector_type(4))) float f32x4;

#define T_ 256
#define B_ 64
#define V_ 10000
#define E_ 400
#define H_ 1152
#define KU 2304      // uniform padded K for all layers (72 kt of 32)
#define XW 416       // padded embedding width (13 kt)
#define KD 416       // decoder K (padded)
#define XET (XW*B_)  // 26624 shorts per timestep in frag-major
#define NBLK 169

#define MFMA16 __builtin_amdgcn_mfma_f32_16x16x32_bf16

// ---------------- prep kernels ----------------

// gate-interleaved weight: dst[(hcol*4+gate)][k] over K=2304, zero-padded.
__global__ __launch_bounds__(256) void prep_wint(
    const float* __restrict__ s1, int w1,
    const float* __restrict__ s2, int off2, int w2, int Hl,
    bf16* __restrict__ dst, long total)
{
    long i = (long)blockIdx.x * 256 + threadIdx.x;
    if (i >= total) return;
    int r = (int)(i / KU), k = (int)(i % KU);
    int hcol = r >> 2, gate = r & 3;
    long srow = (long)gate * Hl + hcol;
    float v = 0.f;
    if (k < w1) v = s1[srow * w1 + k];
    else if (k >= off2 && k < off2 + w2) v = s2[srow * w2 + (k - off2)];
    dst[i] = __float2bfloat16(v);
}

// decoder weight: plain rows, K padded to 416
__global__ __launch_bounds__(256) void prep_wcat(
    const float* __restrict__ s1, int w1,
    bf16* __restrict__ dst, int Ktot, long total)
{
    long i = (long)blockIdx.x * 256 + threadIdx.x;
    if (i >= total) return;
    int k = (int)(i % Ktot);
    long n = i / Ktot;
    dst[i] = __float2bfloat16(k < w1 ? s1[n * w1 + k] : 0.f);
}

__global__ __launch_bounds__(256) void bias_int(
    const float* __restrict__ a, const float* __restrict__ b,
    int Hl, float* __restrict__ d, int n)
{
    int r = blockIdx.x * 256 + threadIdx.x;
    if (r >= n) return;
    int hcol = r >> 2, gate = r & 3;
    d[r] = a[gate * Hl + hcol] + b[gate * Hl + hcol];
}

// embeddings -> frag-major bf16: XEf[t][(k>>3)*64+b][k&7]
__global__ __launch_bounds__(256) void gather_xef(
    const int* __restrict__ x, const float* __restrict__ emb,
    bf16* __restrict__ XEf)
{
    long i = (long)blockIdx.x * 256 + threadIdx.x;
    if (i >= (long)T_ * B_ * XW) return;
    int k = (int)(i % XW);
    int b = (int)((i / XW) % B_);
    int t = (int)(i / ((long)XW * B_));
    float v = (k < E_) ? emb[(long)x[t * B_ + b] * E_ + k] : 0.f;
    XEf[(long)t * XET + (((k >> 3) * 64 + b) << 3) + (k & 7)] = __float2bfloat16(v);
}

// fp32 [B][cols] -> frag-major bf16
__global__ __launch_bounds__(256) void copy_hf(
    const float* __restrict__ src, bf16* __restrict__ dst, int cols, int total)
{
    int i = blockIdx.x * 256 + threadIdx.x;
    if (i >= total) return;
    int k = i % cols, b = i / cols;
    dst[(((k >> 3) * 64 + b) << 3) + (k & 7)] = __float2bfloat16(src[(long)b * cols + k]);
}

__global__ __launch_bounds__(256) void copy_f32(
    const float* __restrict__ src, float* __restrict__ dst, int n)
{
    int i = blockIdx.x * 256 + threadIdx.x;
    if (i < n) dst[i] = src[i];
}

// ---------------- lightweight grid barrier, parallel arrival ----------------
// Arrival: per-WG release store to own flag slot (no RMW serialization).
// WG0 wave0 polls all flags (3/lane + __all), acquire-fences, releases gen.
// Workers spin on gen relaxed, then acquire. Phases monotonic -> no reset.
__device__ __forceinline__ void grid_bar(int* flags, int* gen, int phase) {
    __syncthreads();
    if (threadIdx.x == 0)
        __hip_atomic_store(&flags[blockIdx.x], phase, __ATOMIC_RELEASE, __HIP_MEMORY_SCOPE_AGENT);
    if (blockIdx.x == 0) {
        if (threadIdx.x < 64) {
            const int ln = threadIdx.x;
            for (;;) {
                int f0 = (ln       < NBLK) ? __hip_atomic_load(&flags[ln],       __ATOMIC_RELAXED, __HIP_MEMORY_SCOPE_AGENT) : phase;
                int f1 = (ln + 64  < NBLK) ? __hip_atomic_load(&flags[ln + 64],  __ATOMIC_RELAXED, __HIP_MEMORY_SCOPE_AGENT) : phase;
                int f2 = (ln + 128 < NBLK) ? __hip_atomic_load(&flags[ln + 128], __ATOMIC_RELAXED, __HIP_MEMORY_SCOPE_AGENT) : phase;
                if (__all(f0 >= phase && f1 >= phase && f2 >= phase)) break;
                __builtin_amdgcn_s_sleep(1);
            }
            if (threadIdx.x == 0) {
                __builtin_amdgcn_fence(__ATOMIC_ACQUIRE, "agent");
                __hip_atomic_store(gen, phase, __ATOMIC_RELEASE, __HIP_MEMORY_SCOPE_AGENT);
            }
        }
    } else {
        if (threadIdx.x == 0) {
            while (__hip_atomic_load(gen, __ATOMIC_RELAXED, __HIP_MEMORY_SCOPE_AGENT) < phase)
                __builtin_amdgcn_s_sleep(1);
            (void)__hip_atomic_load(gen, __ATOMIC_ACQUIRE, __HIP_MEMORY_SCOPE_AGENT);
        }
    }
    __syncthreads();
}

// ---------------- weight-stationary persistent LSTM ----------------
// 169 WGs: 0..71 -> L1 group, 72..143 -> L0 group, 144..168 -> L2 group.
// Weights + cell state register-resident; activations frag-major in global;
// 1 barrier/step (skewed pipeline {L0(s+1), L1(s), L2(s-1)}).
__global__ __launch_bounds__(512, 2) void awd_persistent(
    const bf16* __restrict__ XEf,
    const bf16* __restrict__ W0, const bf16* __restrict__ W1, const bf16* __restrict__ W2,
    const float* __restrict__ b0, const float* __restrict__ b1, const float* __restrict__ b2,
    bf16* H0f0, bf16* H0f1, bf16* H1f0, bf16* H1f1, bf16* H2f0, bf16* H2f1,
    float* c0, float* c1, float* c2, bf16* OUTB,
    int* flags, int* gen)
{
    __shared__ float gsm[4][64][65];
    const int bid = blockIdx.x;
    const int tid = threadIdx.x;
    const int lane = tid & 63;
    const int w8 = tid >> 6;
    const int rh = w8 & 1, kq = w8 >> 1;
    const int lh = lane >> 4, l15 = lane & 15;
    const int kq18 = kq * 18;
    const int boff8 = (lh * 64 + l15) * 8;

    int layer, grp;
    if (bid < 72)       { layer = 1; grp = bid; }
    else if (bid < 144) { layer = 0; grp = bid - 72; }
    else                { layer = 2; grp = bid - 144; }

    const bf16* Wp  = (layer == 0) ? W0 : (layer == 1) ? W1 : W2;
    const float* bias = (layer == 0) ? b0 : (layer == 1) ? b1 : b2;
    const float* cbuf = (layer == 0) ? c0 : (layer == 1) ? c1 : c2;
    const int Hl  = (layer == 2) ? 400 : 1152;
    const int bkt = (layer == 0) ? 13 : 36;   // kt where A switches from A1 to A2
    const int nkt = (layer == 1) ? 72 : 49;   // real kt count

    // ---- load weights into registers (once) ----
    short8 wreg[18][2];
    #pragma unroll
    for (int u = 0; u < 18; ++u)
        #pragma unroll
        for (int rt = 0; rt < 2; ++rt) {
            int row = grp * 64 + rh * 32 + rt * 16 + l15;
            int k   = (kq18 + u) * 32 + lh * 8;
            wreg[u][rt] = *(const short8*)(Wp + (long)row * KU + k);
        }

    float myb[2][4];
    #pragma unroll
    for (int e = 0; e < 2; ++e)
        #pragma unroll
        for (int g = 0; g < 4; ++g)
            myb[e][g] = bias[grp * 64 + (w8 + e * 8) * 4 + g];

    // ---- cell state in registers: thread owns (colG = grp*16+w8+e*8, b = lane)
    float creg[2];
    #pragma unroll
    for (int e = 0; e < 2; ++e)
        creg[e] = cbuf[(long)lane * Hl + grp * 16 + w8 + e * 8];

    for (int s = -1; s <= 256; ++s) {
        bool active = (layer == 0) ? (s <= 254)
                    : (layer == 1) ? (s >= 0 && s <= 255)
                                   : (s >= 1);
        if (active) {
            const int p = s & 1, q = p ^ 1;
            const bf16 *A1, *A2; bf16* hfW; bf16* ob = nullptr;
            if (layer == 0) {
                A1 = XEf + (long)(s + 1) * XET;
                A2 = p ? H0f1 : H0f0;
                hfW = q ? H0f1 : H0f0;
            } else if (layer == 1) {
                A1 = p ? H0f1 : H0f0;
                A2 = q ? H1f1 : H1f0;
                hfW = p ? H1f1 : H1f0;
            } else {
                A1 = q ? H1f1 : H1f0;
                A2 = p ? H2f1 : H2f0;
                hfW = q ? H2f1 : H2f0;
                ob = OUTB + (long)(s - 1) * B_ * XW;
            }

            f32x4 acc[2][4];
            #pragma unroll
            for (int rt = 0; rt < 2; ++rt)
                #pragma unroll
                for (int m = 0; m < 4; ++m)
                    acc[rt][m] = (f32x4){0.f, 0.f, 0.f, 0.f};

            #pragma unroll
            for (int u = 0; u < 18; ++u) {
                const int ktg = kq18 + u;
                const bf16* src; int ktL;
                if (ktg < bkt)      { src = A1; ktL = ktg; }
                else if (ktg < nkt) { src = A2; ktL = ktg - bkt; }
                else                { src = A1; ktL = 0; }   // pad: zero weights
                const bf16* pB = src + ktL * 2048 + boff8;
                short8 bf0 = *(const short8*)(pB);
                short8 bf1 = *(const short8*)(pB + 128);
                short8 bf2 = *(const short8*)(pB + 256);
                short8 bf3 = *(const short8*)(pB + 384);
                acc[0][0] = MFMA16(wreg[u][0], bf0, acc[0][0], 0, 0, 0);
                acc[1][0] = MFMA16(wreg[u][1], bf0, acc[1][0], 0, 0, 0);
                acc[0][1] = MFMA16(wreg[u][0], bf1, acc[0][1], 0, 0, 0);
                acc[1][1] = MFMA16(wreg[u][1], bf1, acc[1][1], 0, 0, 0);
                acc[0][2] = MFMA16(wreg[u][0], bf2, acc[0][2], 0, 0, 0);
                acc[1][2] = MFMA16(wreg[u][1], bf2, acc[1][2], 0, 0, 0);
                acc[0][3] = MFMA16(wreg[u][0], bf3, acc[0][3], 0, 0, 0);
                acc[1][3] = MFMA16(wreg[u][1], bf3, acc[1][3], 0, 0, 0);
            }

            __syncthreads();   // protect previous phase's gsm reads
            #pragma unroll
            for (int rt = 0; rt < 2; ++rt)
                #pragma unroll
                for (int m = 0; m < 4; ++m)
                    #pragma unroll
                    for (int r = 0; r < 4; ++r)
                        gsm[kq][rh * 32 + rt * 16 + lh * 4 + r][m * 16 + l15] = acc[rt][m][r];
            __syncthreads();

            // nonlinearity: 1024 outputs (16 cols x 64 batch), 2 per thread
            #pragma unroll
            for (int e = 0; e < 2; ++e) {
                int b = lane;
                int cl = w8 + e * 8;
                float gv[4];
                #pragma unroll
                for (int g = 0; g < 4; ++g)
                    gv[g] = gsm[0][cl * 4 + g][b] + gsm[1][cl * 4 + g][b]
                          + gsm[2][cl * 4 + g][b] + gsm[3][cl * 4 + g][b] + myb[e][g];
                int colG = grp * 16 + cl;
                float c_old = creg[e];
                float i_s = 1.f / (1.f + expf(-gv[0]));
                float f_s = 1.f / (1.f + expf(-gv[1]));
                float o_s = 1.f / (1.f + expf(-gv[3]));
                float c_new = f_s * c_old + i_s * tanhf(gv[2]);
                float hval = o_s * tanhf(c_new);
                creg[e] = c_new;
                bf16 hb = __float2bfloat16(hval);
                hfW[(((colG >> 3) * 64 + b) << 3) + (colG & 7)] = hb;
                if (layer == 2) ob[(long)b * XW + colG] = hb;
            }
        }
        grid_bar(flags, gen, s + 2);
    }
}

// ---------------- decoder GEMM ----------------
__global__ __launch_bounds__(256) void decoder(
    const bf16* __restrict__ A, const bf16* __restrict__ W,
    const float* __restrict__ bias, float* __restrict__ out)
{
    const int tid = threadIdx.x;
    const int lane = tid & 63;
    const int w = tid >> 6;
    const int n0 = blockIdx.x * 64;
    const int m0 = blockIdx.y * 64 + w * 16;
    const int c16 = lane & 15;
    const int kg = lane >> 4;

    f32x4 acc[4];
    for (int i = 0; i < 4; ++i) acc[i] = (f32x4){0.f, 0.f, 0.f, 0.f};

    const bf16* arow = A + (long)(m0 + c16) * KD + kg * 8;
    #pragma unroll
    for (int kt = 0; kt < 13; ++kt) {
        short8 af = *(const short8*)(arow + kt * 32);
        #pragma unroll
        for (int ns = 0; ns < 4; ++ns) {
            int n = n0 + ns * 16 + c16;
            if (n > V_ - 1) n = V_ - 1;
            short8 bfr = *(const short8*)(W + (long)n * KD + kt * 32 + kg * 8);
            acc[ns] = MFMA16(af, bfr, acc[ns], 0, 0, 0);
        }
    }

    #pragma unroll
    for (int ns = 0; ns < 4; ++ns) {
        int col = n0 + ns * 16 + c16;
        if (col < V_) {
            float bv = bias[col];
            #pragma unroll
            for (int r = 0; r < 4; ++r) {
                int row = m0 + kg * 4 + r;
                out[(size_t)row * V_ + col] = acc[ns][r] + bv;
            }
        }
    }
}

// ---------------- host ----------------

extern "C" void kernel_launch(void* const* d_in, const int* in_sizes, int n_in,
                              void* d_out, int out_size, void* d_ws, size_t ws_size,
                              hipStream_t stream)
{
    const int*   x    = (const int*)d_in[0];
    const float* h0   = (const float*)d_in[1];
    const float* h1   = (const float*)d_in[2];
    const float* h2   = (const float*)d_in[3];
    const float* c0   = (const float*)d_in[4];
    const float* c1   = (const float*)d_in[5];
    const float* c2   = (const float*)d_in[6];
    const float* emb  = (const float*)d_in[7];
    const float* Wih0 = (const float*)d_in[8];
    const float* Whh0 = (const float*)d_in[9];
    const float* bih0 = (const float*)d_in[10];
    const float* bhh0 = (const float*)d_in[11];
    const float* Wih1 = (const float*)d_in[12];
    const float* Whh1 = (const float*)d_in[13];
    const float* bih1 = (const float*)d_in[14];
    const float* bhh1 = (const float*)d_in[15];
    const float* Wih2 = (const float*)d_in[16];
    const float* Whh2 = (const float*)d_in[17];
    const float* bih2 = (const float*)d_in[18];
    const float* bhh2 = (const float*)d_in[19];
    const float* decW = (const float*)d_in[20];
    const float* decb = (const float*)d_in[21];

    char* wsb = (char*)d_ws;
    size_t off = 0;
    auto alloc = [&](size_t bytes) -> void* {
        void* ptr = wsb + off;
        off = (off + bytes + 255) & ~(size_t)255;
        return ptr;
    };

    bf16* W0i = (bf16*)alloc((size_t)4608 * KU * 2);
    bf16* W1i = (bf16*)alloc((size_t)4608 * KU * 2);
    bf16* W2i = (bf16*)alloc((size_t)1600 * KU * 2);
    bf16* Wdc = (bf16*)alloc((size_t)V_ * KD * 2);
    float* b0i = (float*)alloc(4608 * 4);
    float* b1i = (float*)alloc(4608 * 4);
    float* b2i = (float*)alloc(1600 * 4);
    bf16* XEf = (bf16*)alloc((size_t)T_ * XET * 2);
    bf16* H0f0 = (bf16*)alloc((size_t)B_ * H_ * 2);
    bf16* H0f1 = (bf16*)alloc((size_t)B_ * H_ * 2);
    bf16* H1f0 = (bf16*)alloc((size_t)B_ * H_ * 2);
    bf16* H1f1 = (bf16*)alloc((size_t)B_ * H_ * 2);
    bf16* H2f0 = (bf16*)alloc((size_t)B_ * XW * 2);
    bf16* H2f1 = (bf16*)alloc((size_t)B_ * XW * 2);
    float* c0b = (float*)alloc((size_t)B_ * H_ * 4);
    float* c1b = (float*)alloc((size_t)B_ * H_ * 4);
    float* c2b = (float*)alloc((size_t)B_ * E_ * 4);
    bf16* OUTB = (bf16*)alloc((size_t)T_ * B_ * XW * 2);
    int* gbar = (int*)alloc(2048);   // flags[0..168]; gen at +448 ints

    auto cdiv = [](long a, long b) { return (int)((a + b - 1) / b); };

    // barrier re-init every launch (ws poisoned once before timing)
    hipMemsetAsync(gbar, 0, 2048, stream);

    // weight prep (gate-interleaved, K padded to 2304)
    prep_wint<<<cdiv(4608L * KU, 256), 256, 0, stream>>>(Wih0, 400,  Whh0, 416,  1152, 1152, W0i, 4608L * KU);
    prep_wint<<<cdiv(4608L * KU, 256), 256, 0, stream>>>(Wih1, 1152, Whh1, 1152, 1152, 1152, W1i, 4608L * KU);
    prep_wint<<<cdiv(1600L * KU, 256), 256, 0, stream>>>(Wih2, 1152, Whh2, 1152, 400,  400,  W2i, 1600L * KU);
    prep_wcat<<<cdiv((long)V_ * KD, 256), 256, 0, stream>>>(decW, 400, Wdc, KD, (long)V_ * KD);
    bias_int<<<cdiv(4608, 256), 256, 0, stream>>>(bih0, bhh0, 1152, b0i, 4608);
    bias_int<<<cdiv(4608, 256), 256, 0, stream>>>(bih1, bhh1, 1152, b1i, 4608);
    bias_int<<<cdiv(1600, 256), 256, 0, stream>>>(bih2, bhh2, 400,  b2i, 1600);
    gather_xef<<<cdiv((long)T_ * B_ * XW, 256), 256, 0, stream>>>(x, emb, XEf);

    // zero pads (h2 frag buffers have cols 400..415 never written; OUTB pads feed decoder)
    hipMemsetAsync(H2f0, 0, (size_t)B_ * XW * 2, stream);
    hipMemsetAsync(H2f1, 0, (size_t)B_ * XW * 2, stream);
    hipMemsetAsync(OUTB, 0, (size_t)T_ * B_ * XW * 2, stream);

    // initial states: h -> frag-major parity-1 buffers, c -> fp32 plain
    copy_hf<<<cdiv(B_ * H_, 256), 256, 0, stream>>>(h0, H0f1, H_, B_ * H_);
    copy_hf<<<cdiv(B_ * H_, 256), 256, 0, stream>>>(h1, H1f1, H_, B_ * H_);
    copy_hf<<<cdiv(B_ * E_, 256), 256, 0, stream>>>(h2, H2f1, E_, B_ * E_);
    copy_f32<<<cdiv(B_ * H_, 256), 256, 0, stream>>>(c0, c0b, B_ * H_);
    copy_f32<<<cdiv(B_ * H_, 256), 256, 0, stream>>>(c1, c1b, B_ * H_);
    copy_f32<<<cdiv(B_ * E_, 256), 256, 0, stream>>>(c2, c2b, B_ * E_);

    // persistent weight-stationary recurrence
    {
        int* flags = gbar;
        int* gen   = gbar + 448;
        void* args[] = {
            (void*)&XEf, (void*)&W0i, (void*)&W1i, (void*)&W2i,
            (void*)&b0i, (void*)&b1i, (void*)&b2i,
            (void*)&H0f0, (void*)&H0f1, (void*)&H1f0, (void*)&H1f1,
            (void*)&H2f0, (void*)&H2f1,
            (void*)&c0b, (void*)&c1b, (void*)&c2b, (void*)&OUTB,
            (void*)&flags, (void*)&gen
        };
        hipLaunchCooperativeKernel((void*)awd_persistent, dim3(NBLK), dim3(512),
                                   args, 0, stream);
    }

    // decoder
    decoder<<<dim3((V_ + 63) / 64, (T_ * B_) / 64), 256, 0, stream>>>(
        OUTB, Wdc, decb, (float*)d_out);
}

// Round 8
// 4796.150 us; speedup vs baseline: 10.4346x; 1.2042x over previous
//
#include <hip/hip_runtime.h>
#include <hip/hip_bf16.h>

typedef __hip_bfloat16 bf16;
typedef __attribute__((ext_vector_type(8))) short short8;
typedef __attribute__((ext_vector_type(4))) float f32x4;

#define T_ 256
#define B_ 64
#define V_ 10000
#define E_ 400
#define H_ 1152
#define KU 2304      // uniform padded K for all layers (72 kt of 32)
#define XW 416       // padded embedding width (13 kt)
#define KD 416       // decoder K (padded)
#define XET (XW*B_)  // shorts per timestep in frag-major
#define NBLK 169

#define MFMA16 __builtin_amdgcn_mfma_f32_16x16x32_bf16
#define ATL(p) __hip_atomic_load((p), __ATOMIC_RELAXED, __HIP_MEMORY_SCOPE_AGENT)
#define ATS(p, v) __hip_atomic_store((p), (v), __ATOMIC_RELAXED, __HIP_MEMORY_SCOPE_AGENT)

// ---------------- prep kernels ----------------

__global__ __launch_bounds__(256) void prep_wint(
    const float* __restrict__ s1, int w1,
    const float* __restrict__ s2, int off2, int w2, int Hl,
    bf16* __restrict__ dst, long total)
{
    long i = (long)blockIdx.x * 256 + threadIdx.x;
    if (i >= total) return;
    int r = (int)(i / KU), k = (int)(i % KU);
    int hcol = r >> 2, gate = r & 3;
    long srow = (long)gate * Hl + hcol;
    float v = 0.f;
    if (k < w1) v = s1[srow * w1 + k];
    else if (k >= off2 && k < off2 + w2) v = s2[srow * w2 + (k - off2)];
    dst[i] = __float2bfloat16(v);
}

__global__ __launch_bounds__(256) void prep_wcat(
    const float* __restrict__ s1, int w1,
    bf16* __restrict__ dst, int Ktot, long total)
{
    long i = (long)blockIdx.x * 256 + threadIdx.x;
    if (i >= total) return;
    int k = (int)(i % Ktot);
    long n = i / Ktot;
    dst[i] = __float2bfloat16(k < w1 ? s1[n * w1 + k] : 0.f);
}

__global__ __launch_bounds__(256) void bias_int(
    const float* __restrict__ a, const float* __restrict__ b,
    int Hl, float* __restrict__ d, int n)
{
    int r = blockIdx.x * 256 + threadIdx.x;
    if (r >= n) return;
    int hcol = r >> 2, gate = r & 3;
    d[r] = a[gate * Hl + hcol] + b[gate * Hl + hcol];
}

__global__ __launch_bounds__(256) void gather_xef(
    const int* __restrict__ x, const float* __restrict__ emb,
    bf16* __restrict__ XEf)
{
    long i = (long)blockIdx.x * 256 + threadIdx.x;
    if (i >= (long)T_ * B_ * XW) return;
    int k = (int)(i % XW);
    int b = (int)((i / XW) % B_);
    int t = (int)(i / ((long)XW * B_));
    float v = (k < E_) ? emb[(long)x[t * B_ + b] * E_ + k] : 0.f;
    XEf[(long)t * XET + (((k >> 3) * 64 + b) << 3) + (k & 7)] = __float2bfloat16(v);
}

__global__ __launch_bounds__(256) void copy_hf(
    const float* __restrict__ src, bf16* __restrict__ dst, int cols, int total)
{
    int i = blockIdx.x * 256 + threadIdx.x;
    if (i >= total) return;
    int k = i % cols, b = i / cols;
    dst[(((k >> 3) * 64 + b) << 3) + (k & 7)] = __float2bfloat16(src[(long)b * cols + k]);
}

__global__ __launch_bounds__(256) void copy_f32(
    const float* __restrict__ src, float* __restrict__ dst, int n)
{
    int i = blockIdx.x * 256 + threadIdx.x;
    if (i < n) dst[i] = src[i];
}

// ------------- fence-free grid barrier (write-through protocol) -------------
// All cross-WG data moves via agent-relaxed atomics (sc0+sc1, L3-coherent),
// so no wbl2/inv is needed: each wave drains its own stores (vmcnt is
// per-wave!), tid0 publishes a flag; WG0 polls flags in parallel, publishes gen.
__device__ __forceinline__ void grid_bar(int* flags, int* gen, int phase) {
    asm volatile("s_waitcnt vmcnt(0)" ::: "memory");  // per-wave: h stores drained to L3
    __syncthreads();
    if (blockIdx.x == 0) {
        if (threadIdx.x < 64) {
            const int ln = threadIdx.x;
            if (ln == 0) ATS(&flags[0], phase);
            for (;;) {
                int f0 = (ln       < NBLK) ? ATL(&flags[ln])       : phase;
                int f1 = (ln + 64  < NBLK) ? ATL(&flags[ln + 64])  : phase;
                int f2 = (ln + 128 < NBLK) ? ATL(&flags[ln + 128]) : phase;
                if (__all(f0 >= phase && f1 >= phase && f2 >= phase)) break;
                __builtin_amdgcn_s_sleep(1);
            }
            if (ln == 0) ATS(gen, phase);
        }
    } else {
        if (threadIdx.x == 0) {
            ATS(&flags[blockIdx.x], phase);
            while (ATL(gen) < phase)
                __builtin_amdgcn_s_sleep(1);
        }
    }
    __syncthreads();
    asm volatile("" ::: "memory");   // no hoisting of next-phase loads above spin
}

// ---------------- weight-stationary persistent LSTM ----------------
struct Frag4 { short8 f0, f1, f2, f3; };

__global__ __launch_bounds__(512, 2) void awd_persistent(
    const bf16* __restrict__ XEf,
    const bf16* __restrict__ W0, const bf16* __restrict__ W1, const bf16* __restrict__ W2,
    const float* __restrict__ b0, const float* __restrict__ b1, const float* __restrict__ b2,
    bf16* H0f0, bf16* H0f1, bf16* H1f0, bf16* H1f1, bf16* H2f0, bf16* H2f1,
    float* c0, float* c1, float* c2, bf16* OUTB,
    int* flags, int* gen)
{
    __shared__ float gsm[4][64][65];
    const int bid = blockIdx.x;
    const int tid = threadIdx.x;
    const int lane = tid & 63;
    const int w8 = tid >> 6;
    const int rh = w8 & 1, kq = w8 >> 1;
    const int lh = lane >> 4, l15 = lane & 15;
    const int kq18 = kq * 18;
    const int boff8 = (lh * 64 + l15) * 8;

    int layer, grp;
    if (bid < 72)       { layer = 1; grp = bid; }
    else if (bid < 144) { layer = 0; grp = bid - 72; }
    else                { layer = 2; grp = bid - 144; }

    const bf16* Wp  = (layer == 0) ? W0 : (layer == 1) ? W1 : W2;
    const float* bias = (layer == 0) ? b0 : (layer == 1) ? b1 : b2;
    const float* cbuf = (layer == 0) ? c0 : (layer == 1) ? c1 : c2;
    const int Hl  = (layer == 2) ? 400 : 1152;
    const int bkt = (layer == 0) ? 13 : 36;
    const int nkt = (layer == 1) ? 72 : 49;

    // ---- weights into registers (once) ----
    short8 wreg[18][2];
    #pragma unroll
    for (int u = 0; u < 18; ++u)
        #pragma unroll
        for (int rt = 0; rt < 2; ++rt) {
            int row = grp * 64 + rh * 32 + rt * 16 + l15;
            int k   = (kq18 + u) * 32 + lh * 8;
            wreg[u][rt] = *(const short8*)(Wp + (long)row * KU + k);
        }

    float myb[2][4];
    #pragma unroll
    for (int e = 0; e < 2; ++e)
        #pragma unroll
        for (int g = 0; g < 4; ++g)
            myb[e][g] = bias[grp * 64 + (w8 + e * 8) * 4 + g];

    float creg[2];
    #pragma unroll
    for (int e = 0; e < 2; ++e)
        creg[e] = cbuf[(long)lane * Hl + grp * 16 + w8 + e * 8];

    for (int s = -1; s <= 256; ++s) {
        bool active = (layer == 0) ? (s <= 254)
                    : (layer == 1) ? (s >= 0 && s <= 255)
                                   : (s >= 1);
        if (active) {
            const int p = s & 1, q = p ^ 1;
            const bf16 *A1, *A2; bf16* hfW; bf16* ob = nullptr;
            if (layer == 0) {
                A1 = XEf + (long)(s + 1) * XET;
                A2 = p ? H0f1 : H0f0;
                hfW = q ? H0f1 : H0f0;
            } else if (layer == 1) {
                A1 = p ? H0f1 : H0f0;
                A2 = q ? H1f1 : H1f0;
                hfW = p ? H1f1 : H1f0;
            } else {
                A1 = q ? H1f1 : H1f0;
                A2 = p ? H2f1 : H2f0;
                hfW = q ? H2f1 : H2f0;
                ob = OUTB + (long)(s - 1) * B_ * XW;
            }

            // L3-coherent frag load. Fragments sit at +0,+128,+256,+384 bf16
            // elements = +0,+256,+512,+768 BYTES = qp + 0/32/64/96 (8B units).
            auto loadf = [&](int u) -> Frag4 {
                const int ktg = kq18 + u;
                const bf16* src; int ktL;
                if (ktg < bkt)      { src = A1; ktL = ktg; }
                else if (ktg < nkt) { src = A2; ktL = ktg - bkt; }
                else                { src = A1; ktL = 0; }   // pad: zero weights
                const unsigned long long* qp =
                    (const unsigned long long*)(src + ktL * 2048 + boff8);
                union { unsigned long long u2[2]; short8 s8; } a, b, c, d;
                a.u2[0] = ATL(qp);      a.u2[1] = ATL(qp + 1);
                b.u2[0] = ATL(qp + 32); b.u2[1] = ATL(qp + 33);
                c.u2[0] = ATL(qp + 64); c.u2[1] = ATL(qp + 65);
                d.u2[0] = ATL(qp + 96); d.u2[1] = ATL(qp + 97);
                Frag4 r; r.f0 = a.s8; r.f1 = b.s8; r.f2 = c.s8; r.f3 = d.s8;
                return r;
            };

            f32x4 acc[2][4];
            #pragma unroll
            for (int rt = 0; rt < 2; ++rt)
                #pragma unroll
                for (int m = 0; m < 4; ++m)
                    acc[rt][m] = (f32x4){0.f, 0.f, 0.f, 0.f};

            auto domfma = [&](int u, const Frag4& f) {
                acc[0][0] = MFMA16(wreg[u][0], f.f0, acc[0][0], 0, 0, 0);
                acc[1][0] = MFMA16(wreg[u][1], f.f0, acc[1][0], 0, 0, 0);
                acc[0][1] = MFMA16(wreg[u][0], f.f1, acc[0][1], 0, 0, 0);
                acc[1][1] = MFMA16(wreg[u][1], f.f1, acc[1][1], 0, 0, 0);
                acc[0][2] = MFMA16(wreg[u][0], f.f2, acc[0][2], 0, 0, 0);
                acc[1][2] = MFMA16(wreg[u][1], f.f2, acc[1][2], 0, 0, 0);
                acc[0][3] = MFMA16(wreg[u][0], f.f3, acc[0][3], 0, 0, 0);
                acc[1][3] = MFMA16(wreg[u][1], f.f3, acc[1][3], 0, 0, 0);
            };

            // 2-deep software pipeline; all indices compile-time after unroll
            {
                Frag4 fa = loadf(0);
                Frag4 fb = loadf(1);
                #pragma unroll
                for (int u = 0; u < 18; u += 2) {
                    Frag4 fc = (u + 2 < 18) ? loadf(u + 2) : fa;
                    domfma(u, fa);
                    Frag4 fd = (u + 3 < 18) ? loadf(u + 3) : fb;
                    domfma(u + 1, fb);
                    fa = fc; fb = fd;
                }
            }

            __syncthreads();   // protect previous phase's gsm reads
            #pragma unroll
            for (int rt = 0; rt < 2; ++rt)
                #pragma unroll
                for (int m = 0; m < 4; ++m)
                    #pragma unroll
                    for (int r = 0; r < 4; ++r)
                        gsm[kq][rh * 32 + rt * 16 + lh * 4 + r][m * 16 + l15] = acc[rt][m][r];
            __syncthreads();

            // nonlinearity: 16 cols x 64 batch, 2 per thread
            #pragma unroll
            for (int e = 0; e < 2; ++e) {
                int b = lane;
                int cl = w8 + e * 8;
                float gv[4];
                #pragma unroll
                for (int g = 0; g < 4; ++g)
                    gv[g] = gsm[0][cl * 4 + g][b] + gsm[1][cl * 4 + g][b]
                          + gsm[2][cl * 4 + g][b] + gsm[3][cl * 4 + g][b] + myb[e][g];
                int colG = grp * 16 + cl;
                float c_old = creg[e];
                float i_s = 1.f / (1.f + expf(-gv[0]));
                float f_s = 1.f / (1.f + expf(-gv[1]));
                float o_s = 1.f / (1.f + expf(-gv[3]));
                float c_new = f_s * c_old + i_s * tanhf(gv[2]);
                float hval = o_s * tanhf(c_new);
                creg[e] = c_new;
                bf16 hb = __float2bfloat16(hval);
                unsigned short hbits;
                __builtin_memcpy(&hbits, &hb, 2);
                ATS((unsigned short*)&hfW[(((colG >> 3) * 64 + b) << 3) + (colG & 7)], hbits);
                if (layer == 2) ob[(long)b * XW + colG] = hb;   // cross-kernel only: plain
            }
        }
        grid_bar(flags, gen, s + 2);
    }
}

// ---------------- decoder GEMM ----------------
__global__ __launch_bounds__(256) void decoder(
    const bf16* __restrict__ A, const bf16* __restrict__ W,
    const float* __restrict__ bias, float* __restrict__ out)
{
    const int tid = threadIdx.x;
    const int lane = tid & 63;
    const int w = tid >> 6;
    const int n0 = blockIdx.x * 64;
    const int m0 = blockIdx.y * 64 + w * 16;
    const int c16 = lane & 15;
    const int kg = lane >> 4;

    f32x4 acc[4];
    for (int i = 0; i < 4; ++i) acc[i] = (f32x4){0.f, 0.f, 0.f, 0.f};

    const bf16* arow = A + (long)(m0 + c16) * KD + kg * 8;
    #pragma unroll
    for (int kt = 0; kt < 13; ++kt) {
        short8 af = *(const short8*)(arow + kt * 32);
        #pragma unroll
        for (int ns = 0; ns < 4; ++ns) {
            int n = n0 + ns * 16 + c16;
            if (n > V_ - 1) n = V_ - 1;
            short8 bfr = *(const short8*)(W + (long)n * KD + kt * 32 + kg * 8);
            acc[ns] = MFMA16(af, bfr, acc[ns], 0, 0, 0);
        }
    }

    #pragma unroll
    for (int ns = 0; ns < 4; ++ns) {
        int col = n0 + ns * 16 + c16;
        if (col < V_) {
            float bv = bias[col];
            #pragma unroll
            for (int r = 0; r < 4; ++r) {
                int row = m0 + kg * 4 + r;
                out[(size_t)row * V_ + col] = acc[ns][r] + bv;
            }
        }
    }
}

// ---------------- host ----------------

extern "C" void kernel_launch(void* const* d_in, const int* in_sizes, int n_in,
                              void* d_out, int out_size, void* d_ws, size_t ws_size,
                              hipStream_t stream)
{
    const int*   x    = (const int*)d_in[0];
    const float* h0   = (const float*)d_in[1];
    const float* h1   = (const float*)d_in[2];
    const float* h2   = (const float*)d_in[3];
    const float* c0   = (const float*)d_in[4];
    const float* c1   = (const float*)d_in[5];
    const float* c2   = (const float*)d_in[6];
    const float* emb  = (const float*)d_in[7];
    const float* Wih0 = (const float*)d_in[8];
    const float* Whh0 = (const float*)d_in[9];
    const float* bih0 = (const float*)d_in[10];
    const float* bhh0 = (const float*)d_in[11];
    const float* Wih1 = (const float*)d_in[12];
    const float* Whh1 = (const float*)d_in[13];
    const float* bih1 = (const float*)d_in[14];
    const float* bhh1 = (const float*)d_in[15];
    const float* Wih2 = (const float*)d_in[16];
    const float* Whh2 = (const float*)d_in[17];
    const float* bih2 = (const float*)d_in[18];
    const float* bhh2 = (const float*)d_in[19];
    const float* decW = (const float*)d_in[20];
    const float* decb = (const float*)d_in[21];

    char* wsb = (char*)d_ws;
    size_t off = 0;
    auto alloc = [&](size_t bytes) -> void* {
        void* ptr = wsb + off;
        off = (off + bytes + 255) & ~(size_t)255;
        return ptr;
    };

    bf16* W0i = (bf16*)alloc((size_t)4608 * KU * 2);
    bf16* W1i = (bf16*)alloc((size_t)4608 * KU * 2);
    bf16* W2i = (bf16*)alloc((size_t)1600 * KU * 2);
    bf16* Wdc = (bf16*)alloc((size_t)V_ * KD * 2);
    float* b0i = (float*)alloc(4608 * 4);
    float* b1i = (float*)alloc(4608 * 4);
    float* b2i = (float*)alloc(1600 * 4);
    bf16* XEf = (bf16*)alloc((size_t)T_ * XET * 2);
    bf16* H0f0 = (bf16*)alloc((size_t)B_ * H_ * 2);
    bf16* H0f1 = (bf16*)alloc((size_t)B_ * H_ * 2);
    bf16* H1f0 = (bf16*)alloc((size_t)B_ * H_ * 2);
    bf16* H1f1 = (bf16*)alloc((size_t)B_ * H_ * 2);
    bf16* H2f0 = (bf16*)alloc((size_t)B_ * XW * 2);
    bf16* H2f1 = (bf16*)alloc((size_t)B_ * XW * 2);
    float* c0b = (float*)alloc((size_t)B_ * H_ * 4);
    float* c1b = (float*)alloc((size_t)B_ * H_ * 4);
    float* c2b = (float*)alloc((size_t)B_ * E_ * 4);
    bf16* OUTB = (bf16*)alloc((size_t)T_ * B_ * XW * 2);
    int* gbar = (int*)alloc(2048);   // flags[0..168]; gen at +448 ints

    auto cdiv = [](long a, long b) { return (int)((a + b - 1) / b); };

    hipMemsetAsync(gbar, 0, 2048, stream);

    prep_wint<<<cdiv(4608L * KU, 256), 256, 0, stream>>>(Wih0, 400,  Whh0, 416,  1152, 1152, W0i, 4608L * KU);
    prep_wint<<<cdiv(4608L * KU, 256), 256, 0, stream>>>(Wih1, 1152, Whh1, 1152, 1152, 1152, W1i, 4608L * KU);
    prep_wint<<<cdiv(1600L * KU, 256), 256, 0, stream>>>(Wih2, 1152, Whh2, 1152, 400,  400,  W2i, 1600L * KU);
    prep_wcat<<<cdiv((long)V_ * KD, 256), 256, 0, stream>>>(decW, 400, Wdc, KD, (long)V_ * KD);
    bias_int<<<cdiv(4608, 256), 256, 0, stream>>>(bih0, bhh0, 1152, b0i, 4608);
    bias_int<<<cdiv(4608, 256), 256, 0, stream>>>(bih1, bhh1, 1152, b1i, 4608);
    bias_int<<<cdiv(1600, 256), 256, 0, stream>>>(bih2, bhh2, 400,  b2i, 1600);
    gather_xef<<<cdiv((long)T_ * B_ * XW, 256), 256, 0, stream>>>(x, emb, XEf);

    hipMemsetAsync(H2f0, 0, (size_t)B_ * XW * 2, stream);
    hipMemsetAsync(H2f1, 0, (size_t)B_ * XW * 2, stream);
    hipMemsetAsync(OUTB, 0, (size_t)T_ * B_ * XW * 2, stream);

    copy_hf<<<cdiv(B_ * H_, 256), 256, 0, stream>>>(h0, H0f1, H_, B_ * H_);
    copy_hf<<<cdiv(B_ * H_, 256), 256, 0, stream>>>(h1, H1f1, H_, B_ * H_);
    copy_hf<<<cdiv(B_ * E_, 256), 256, 0, stream>>>(h2, H2f1, E_, B_ * E_);
    copy_f32<<<cdiv(B_ * H_, 256), 256, 0, stream>>>(c0, c0b, B_ * H_);
    copy_f32<<<cdiv(B_ * H_, 256), 256, 0, stream>>>(c1, c1b, B_ * H_);
    copy_f32<<<cdiv(B_ * E_, 256), 256, 0, stream>>>(c2, c2b, B_ * E_);

    {
        int* flags = gbar;
        int* gen   = gbar + 448;
        void* args[] = {
            (void*)&XEf, (void*)&W0i, (void*)&W1i, (void*)&W2i,
            (void*)&b0i, (void*)&b1i, (void*)&b2i,
            (void*)&H0f0, (void*)&H0f1, (void*)&H1f0, (void*)&H1f1,
            (void*)&H2f0, (void*)&H2f1,
            (void*)&c0b, (void*)&c1b, (void*)&c2b, (void*)&OUTB,
            (void*)&flags, (void*)&gen
        };
        hipLaunchCooperativeKernel((void*)awd_persistent, dim3(NBLK), dim3(512),
                                   args, 0, stream);
    }

    decoder<<<dim3((V_ + 63) / 64, (T_ * B_) / 64), 256, 0, stream>>>(
        OUTB, Wdc, decb, (float*)d_out);
}

// Round 9
// 4324.789 us; speedup vs baseline: 11.5719x; 1.1090x over previous
//
#include <hip/hip_runtime.h>
#include <hip/hip_bf16.h>

typedef __hip_bfloat16 bf16;
typedef __attribute__((ext_vector_type(8))) short short8;
typedef __attribute__((ext_vector_type(4))) float f32x4;

#define T_ 256
#define B_ 64
#define V_ 10000
#define E_ 400
#define H_ 1152
#define KU 2304      // uniform padded K for weight buffers (72 kt of 32)
#define XW 416       // padded embedding width (13 kt)
#define KD 416       // decoder K (padded)
#define XET (XW*B_)  // shorts per timestep in frag-major
#define NBLK 169

#define MFMA16 __builtin_amdgcn_mfma_f32_16x16x32_bf16
#define ATL(p) __hip_atomic_load((p), __ATOMIC_RELAXED, __HIP_MEMORY_SCOPE_AGENT)
#define ATS(p, v) __hip_atomic_store((p), (v), __ATOMIC_RELAXED, __HIP_MEMORY_SCOPE_AGENT)

// ---------------- prep kernels ----------------

__global__ __launch_bounds__(256) void prep_wint(
    const float* __restrict__ s1, int w1,
    const float* __restrict__ s2, int off2, int w2, int Hl,
    bf16* __restrict__ dst, long total)
{
    long i = (long)blockIdx.x * 256 + threadIdx.x;
    if (i >= total) return;
    int r = (int)(i / KU), k = (int)(i % KU);
    int hcol = r >> 2, gate = r & 3;
    long srow = (long)gate * Hl + hcol;
    float v = 0.f;
    if (k < w1) v = s1[srow * w1 + k];
    else if (k >= off2 && k < off2 + w2) v = s2[srow * w2 + (k - off2)];
    dst[i] = __float2bfloat16(v);
}

__global__ __launch_bounds__(256) void prep_wcat(
    const float* __restrict__ s1, int w1,
    bf16* __restrict__ dst, int Ktot, long total)
{
    long i = (long)blockIdx.x * 256 + threadIdx.x;
    if (i >= total) return;
    int k = (int)(i % Ktot);
    long n = i / Ktot;
    dst[i] = __float2bfloat16(k < w1 ? s1[n * w1 + k] : 0.f);
}

__global__ __launch_bounds__(256) void bias_int(
    const float* __restrict__ a, const float* __restrict__ b,
    int Hl, float* __restrict__ d, int n)
{
    int r = blockIdx.x * 256 + threadIdx.x;
    if (r >= n) return;
    int hcol = r >> 2, gate = r & 3;
    d[r] = a[gate * Hl + hcol] + b[gate * Hl + hcol];
}

__global__ __launch_bounds__(256) void gather_xef(
    const int* __restrict__ x, const float* __restrict__ emb,
    bf16* __restrict__ XEf)
{
    long i = (long)blockIdx.x * 256 + threadIdx.x;
    if (i >= (long)T_ * B_ * XW) return;
    int k = (int)(i % XW);
    int b = (int)((i / XW) % B_);
    int t = (int)(i / ((long)XW * B_));
    float v = (k < E_) ? emb[(long)x[t * B_ + b] * E_ + k] : 0.f;
    XEf[(long)t * XET + (((k >> 3) * 64 + b) << 3) + (k & 7)] = __float2bfloat16(v);
}

__global__ __launch_bounds__(256) void copy_hf(
    const float* __restrict__ src, bf16* __restrict__ dst, int cols, int total)
{
    int i = blockIdx.x * 256 + threadIdx.x;
    if (i >= total) return;
    int k = i % cols, b = i / cols;
    dst[(((k >> 3) * 64 + b) << 3) + (k & 7)] = __float2bfloat16(src[(long)b * cols + k]);
}

__global__ __launch_bounds__(256) void copy_f32(
    const float* __restrict__ src, float* __restrict__ dst, int n)
{
    int i = blockIdx.x * 256 + threadIdx.x;
    if (i < n) dst[i] = src[i];
}

// ------------- fence-free grid barrier (write-through protocol) -------------
__device__ __forceinline__ void grid_bar(int* flags, int* gen, int phase) {
    asm volatile("s_waitcnt vmcnt(0)" ::: "memory");  // per-wave: h stores drained to L3
    __syncthreads();
    if (blockIdx.x == 0) {
        if (threadIdx.x < 64) {
            const int ln = threadIdx.x;
            if (ln == 0) ATS(&flags[0], phase);
            for (;;) {
                int f0 = (ln       < NBLK) ? ATL(&flags[ln])       : phase;
                int f1 = (ln + 64  < NBLK) ? ATL(&flags[ln + 64])  : phase;
                int f2 = (ln + 128 < NBLK) ? ATL(&flags[ln + 128]) : phase;
                if (__all(f0 >= phase && f1 >= phase && f2 >= phase)) break;
                __builtin_amdgcn_s_sleep(1);
            }
            if (ln == 0) ATS(gen, phase);
        }
    } else {
        if (threadIdx.x == 0) {
            ATS(&flags[blockIdx.x], phase);
            while (ATL(gen) < phase)
                __builtin_amdgcn_s_sleep(1);
        }
    }
    __syncthreads();
    asm volatile("" ::: "memory");   // no hoisting of next-phase loads above spin
}

// ------------- weight-stationary persistent LSTM, 8-way K split -------------
// 169 WGs: 0..71 L1, 72..143 L0, 144..168 L2. Each WG: 16 hidden cols
// (64 gate-interleaved rows). Wave w8 owns K-slice [w8*KT, (w8+1)*KT) kt;
// covers all 4 row-tiles -> every B-frag loaded exactly once per WG.
// Pad trimmed: KT = 9 (L1, exact) / 7 (L0,L2: 49 real kt -> 56).
struct Frag4 { short8 f0, f1, f2, f3; };

__global__ __launch_bounds__(512, 2) void awd_persistent(
    const bf16* __restrict__ XEf,
    const bf16* __restrict__ W0, const bf16* __restrict__ W1, const bf16* __restrict__ W2,
    const float* __restrict__ b0, const float* __restrict__ b1, const float* __restrict__ b2,
    bf16* H0f0, bf16* H0f1, bf16* H1f0, bf16* H1f1, bf16* H2f0, bf16* H2f1,
    float* c0, float* c1, float* c2, bf16* OUTB,
    int* flags, int* gen)
{
    __shared__ float gsm[4][64][65];
    const int bid = blockIdx.x;
    const int tid = threadIdx.x;
    const int lane = tid & 63;
    const int w8 = tid >> 6;              // K-slice index 0..7
    const int lh = lane >> 4, l15 = lane & 15;
    const int boff8 = (lh * 64 + l15) * 8;

    int layer, grp;
    if (bid < 72)       { layer = 1; grp = bid; }
    else if (bid < 144) { layer = 0; grp = bid - 72; }
    else                { layer = 2; grp = bid - 144; }

    const bf16* Wp  = (layer == 0) ? W0 : (layer == 1) ? W1 : W2;
    const float* bias = (layer == 0) ? b0 : (layer == 1) ? b1 : b2;
    const float* cbuf = (layer == 0) ? c0 : (layer == 1) ? c1 : c2;
    const int Hl  = (layer == 2) ? 400 : 1152;
    const int bkt = (layer == 0) ? 13 : 36;   // kt where A switches A1 -> A2
    const int nkt = (layer == 1) ? 72 : 49;   // real kt count
    const int KT  = (layer == 1) ? 9  : 7;    // u-steps per wave
    const int kbase = w8 * KT;

    // ---- weights into registers (once); all indices compile-time ----
    short8 wreg[9][4];
    #pragma unroll
    for (int u = 0; u < 9; ++u)
        if (u < KT) {
            #pragma unroll
            for (int rt = 0; rt < 4; ++rt) {
                int row = grp * 64 + rt * 16 + l15;
                int k   = (kbase + u) * 32 + lh * 8;
                wreg[u][rt] = *(const short8*)(Wp + (long)row * KU + k);
            }
        }

    float myb[2][4];
    #pragma unroll
    for (int e = 0; e < 2; ++e)
        #pragma unroll
        for (int g = 0; g < 4; ++g)
            myb[e][g] = bias[grp * 64 + (w8 + e * 8) * 4 + g];

    float creg[2];
    #pragma unroll
    for (int e = 0; e < 2; ++e)
        creg[e] = cbuf[(long)lane * Hl + grp * 16 + w8 + e * 8];

    for (int s = -1; s <= 256; ++s) {
        bool active = (layer == 0) ? (s <= 254)
                    : (layer == 1) ? (s >= 0 && s <= 255)
                                   : (s >= 1);
        if (active) {
            const int p = s & 1, q = p ^ 1;
            const bf16 *A1, *A2; bf16* hfW; bf16* ob = nullptr;
            if (layer == 0) {
                A1 = XEf + (long)(s + 1) * XET;
                A2 = p ? H0f1 : H0f0;
                hfW = q ? H0f1 : H0f0;
            } else if (layer == 1) {
                A1 = p ? H0f1 : H0f0;
                A2 = q ? H1f1 : H1f0;
                hfW = p ? H1f1 : H1f0;
            } else {
                A1 = q ? H1f1 : H1f0;
                A2 = p ? H2f1 : H2f0;
                hfW = q ? H2f1 : H2f0;
                ob = OUTB + (long)(s - 1) * B_ * XW;
            }

            // L3-coherent frag load: 4 batch-quarter frags of one kt block.
            // Frags at +0,+128,+256,+384 shorts = qp + 0/32/64/96 (8B units).
            auto loadf = [&](int u) -> Frag4 {
                const int ktg = kbase + u;
                const bf16* src; int ktL;
                if (ktg < bkt)      { src = A1; ktL = ktg; }
                else if (ktg < nkt) { src = A2; ktL = ktg - bkt; }
                else                { src = A1; ktL = 0; }   // pad: zero weights
                const unsigned long long* qp =
                    (const unsigned long long*)(src + ktL * 2048 + boff8);
                union { unsigned long long u2[2]; short8 s8; } a, b, c, d;
                a.u2[0] = ATL(qp);      a.u2[1] = ATL(qp + 1);
                b.u2[0] = ATL(qp + 32); b.u2[1] = ATL(qp + 33);
                c.u2[0] = ATL(qp + 64); c.u2[1] = ATL(qp + 65);
                d.u2[0] = ATL(qp + 96); d.u2[1] = ATL(qp + 97);
                Frag4 r; r.f0 = a.s8; r.f1 = b.s8; r.f2 = c.s8; r.f3 = d.s8;
                return r;
            };

            f32x4 acc[4][4];
            #pragma unroll
            for (int rt = 0; rt < 4; ++rt)
                #pragma unroll
                for (int m = 0; m < 4; ++m)
                    acc[rt][m] = (f32x4){0.f, 0.f, 0.f, 0.f};

            auto domfma = [&](int u, const Frag4& f) {
                #pragma unroll
                for (int rt = 0; rt < 4; ++rt) {
                    acc[rt][0] = MFMA16(wreg[u][rt], f.f0, acc[rt][0], 0, 0, 0);
                    acc[rt][1] = MFMA16(wreg[u][rt], f.f1, acc[rt][1], 0, 0, 0);
                    acc[rt][2] = MFMA16(wreg[u][rt], f.f2, acc[rt][2], 0, 0, 0);
                    acc[rt][3] = MFMA16(wreg[u][rt], f.f3, acc[rt][3], 0, 0, 0);
                }
            };

            // 1-ahead pipeline (L3-BW bound; 8 loads in flight per wave)
            {
                Frag4 cur = loadf(0);
                #pragma unroll
                for (int u = 0; u < 9; ++u) {
                    if (u < KT) {
                        Frag4 nxt = cur;
                        if (u + 1 < KT) nxt = loadf(u + 1);
                        domfma(u, cur);
                        cur = nxt;
                    }
                }
            }

            // partial-sum merge: waves 4-7 store, waves 0-3 accumulate
            __syncthreads();   // previous phase's gsm readers done
            if (w8 >= 4) {
                #pragma unroll
                for (int rt = 0; rt < 4; ++rt)
                    #pragma unroll
                    for (int m = 0; m < 4; ++m)
                        #pragma unroll
                        for (int r = 0; r < 4; ++r)
                            gsm[w8 - 4][rt * 16 + lh * 4 + r][m * 16 + l15] = acc[rt][m][r];
            }
            __syncthreads();
            if (w8 < 4) {
                #pragma unroll
                for (int rt = 0; rt < 4; ++rt)
                    #pragma unroll
                    for (int m = 0; m < 4; ++m)
                        #pragma unroll
                        for (int r = 0; r < 4; ++r)
                            gsm[w8][rt * 16 + lh * 4 + r][m * 16 + l15] += acc[rt][m][r];
            }
            __syncthreads();

            // nonlinearity: 16 cols x 64 batch, 2 per thread
            #pragma unroll
            for (int e = 0; e < 2; ++e) {
                int b = lane;
                int cl = w8 + e * 8;
                float gv[4];
                #pragma unroll
                for (int g = 0; g < 4; ++g)
                    gv[g] = gsm[0][cl * 4 + g][b] + gsm[1][cl * 4 + g][b]
                          + gsm[2][cl * 4 + g][b] + gsm[3][cl * 4 + g][b] + myb[e][g];
                int colG = grp * 16 + cl;
                float c_old = creg[e];
                float i_s = 1.f / (1.f + expf(-gv[0]));
                float f_s = 1.f / (1.f + expf(-gv[1]));
                float o_s = 1.f / (1.f + expf(-gv[3]));
                float c_new = f_s * c_old + i_s * tanhf(gv[2]);
                float hval = o_s * tanhf(c_new);
                creg[e] = c_new;
                bf16 hb = __float2bfloat16(hval);
                unsigned short hbits;
                __builtin_memcpy(&hbits, &hb, 2);
                ATS((unsigned short*)&hfW[(((colG >> 3) * 64 + b) << 3) + (colG & 7)], hbits);
                if (layer == 2) ob[(long)b * XW + colG] = hb;   // cross-kernel only: plain
            }
        }
        grid_bar(flags, gen, s + 2);
    }
}

// ---------------- decoder GEMM ----------------
__global__ __launch_bounds__(256) void decoder(
    const bf16* __restrict__ A, const bf16* __restrict__ W,
    const float* __restrict__ bias, float* __restrict__ out)
{
    const int tid = threadIdx.x;
    const int lane = tid & 63;
    const int w = tid >> 6;
    const int n0 = blockIdx.x * 64;
    const int m0 = blockIdx.y * 64 + w * 16;
    const int c16 = lane & 15;
    const int kg = lane >> 4;

    f32x4 acc[4];
    for (int i = 0; i < 4; ++i) acc[i] = (f32x4){0.f, 0.f, 0.f, 0.f};

    const bf16* arow = A + (long)(m0 + c16) * KD + kg * 8;
    #pragma unroll
    for (int kt = 0; kt < 13; ++kt) {
        short8 af = *(const short8*)(arow + kt * 32);
        #pragma unroll
        for (int ns = 0; ns < 4; ++ns) {
            int n = n0 + ns * 16 + c16;
            if (n > V_ - 1) n = V_ - 1;
            short8 bfr = *(const short8*)(W + (long)n * KD + kt * 32 + kg * 8);
            acc[ns] = MFMA16(af, bfr, acc[ns], 0, 0, 0);
        }
    }

    #pragma unroll
    for (int ns = 0; ns < 4; ++ns) {
        int col = n0 + ns * 16 + c16;
        if (col < V_) {
            float bv = bias[col];
            #pragma unroll
            for (int r = 0; r < 4; ++r) {
                int row = m0 + kg * 4 + r;
                out[(size_t)row * V_ + col] = acc[ns][r] + bv;
            }
        }
    }
}

// ---------------- host ----------------

extern "C" void kernel_launch(void* const* d_in, const int* in_sizes, int n_in,
                              void* d_out, int out_size, void* d_ws, size_t ws_size,
                              hipStream_t stream)
{
    const int*   x    = (const int*)d_in[0];
    const float* h0   = (const float*)d_in[1];
    const float* h1   = (const float*)d_in[2];
    const float* h2   = (const float*)d_in[3];
    const float* c0   = (const float*)d_in[4];
    const float* c1   = (const float*)d_in[5];
    const float* c2   = (const float*)d_in[6];
    const float* emb  = (const float*)d_in[7];
    const float* Wih0 = (const float*)d_in[8];
    const float* Whh0 = (const float*)d_in[9];
    const float* bih0 = (const float*)d_in[10];
    const float* bhh0 = (const float*)d_in[11];
    const float* Wih1 = (const float*)d_in[12];
    const float* Whh1 = (const float*)d_in[13];
    const float* bih1 = (const float*)d_in[14];
    const float* bhh1 = (const float*)d_in[15];
    const float* Wih2 = (const float*)d_in[16];
    const float* Whh2 = (const float*)d_in[17];
    const float* bih2 = (const float*)d_in[18];
    const float* bhh2 = (const float*)d_in[19];
    const float* decW = (const float*)d_in[20];
    const float* decb = (const float*)d_in[21];

    char* wsb = (char*)d_ws;
    size_t off = 0;
    auto alloc = [&](size_t bytes) -> void* {
        void* ptr = wsb + off;
        off = (off + bytes + 255) & ~(size_t)255;
        return ptr;
    };

    bf16* W0i = (bf16*)alloc((size_t)4608 * KU * 2);
    bf16* W1i = (bf16*)alloc((size_t)4608 * KU * 2);
    bf16* W2i = (bf16*)alloc((size_t)1600 * KU * 2);
    bf16* Wdc = (bf16*)alloc((size_t)V_ * KD * 2);
    float* b0i = (float*)alloc(4608 * 4);
    float* b1i = (float*)alloc(4608 * 4);
    float* b2i = (float*)alloc(1600 * 4);
    bf16* XEf = (bf16*)alloc((size_t)T_ * XET * 2);
    bf16* H0f0 = (bf16*)alloc((size_t)B_ * H_ * 2);
    bf16* H0f1 = (bf16*)alloc((size_t)B_ * H_ * 2);
    bf16* H1f0 = (bf16*)alloc((size_t)B_ * H_ * 2);
    bf16* H1f1 = (bf16*)alloc((size_t)B_ * H_ * 2);
    bf16* H2f0 = (bf16*)alloc((size_t)B_ * XW * 2);
    bf16* H2f1 = (bf16*)alloc((size_t)B_ * XW * 2);
    float* c0b = (float*)alloc((size_t)B_ * H_ * 4);
    float* c1b = (float*)alloc((size_t)B_ * H_ * 4);
    float* c2b = (float*)alloc((size_t)B_ * E_ * 4);
    bf16* OUTB = (bf16*)alloc((size_t)T_ * B_ * XW * 2);
    int* gbar = (int*)alloc(2048);   // flags[0..168]; gen at +448 ints

    auto cdiv = [](long a, long b) { return (int)((a + b - 1) / b); };

    hipMemsetAsync(gbar, 0, 2048, stream);

    prep_wint<<<cdiv(4608L * KU, 256), 256, 0, stream>>>(Wih0, 400,  Whh0, 416,  1152, 1152, W0i, 4608L * KU);
    prep_wint<<<cdiv(4608L * KU, 256), 256, 0, stream>>>(Wih1, 1152, Whh1, 1152, 1152, 1152, W1i, 4608L * KU);
    prep_wint<<<cdiv(1600L * KU, 256), 256, 0, stream>>>(Wih2, 1152, Whh2, 1152, 400,  400,  W2i, 1600L * KU);
    prep_wcat<<<cdiv((long)V_ * KD, 256), 256, 0, stream>>>(decW, 400, Wdc, KD, (long)V_ * KD);
    bias_int<<<cdiv(4608, 256), 256, 0, stream>>>(bih0, bhh0, 1152, b0i, 4608);
    bias_int<<<cdiv(4608, 256), 256, 0, stream>>>(bih1, bhh1, 1152, b1i, 4608);
    bias_int<<<cdiv(1600, 256), 256, 0, stream>>>(bih2, bhh2, 400,  b2i, 1600);
    gather_xef<<<cdiv((long)T_ * B_ * XW, 256), 256, 0, stream>>>(x, emb, XEf);

    hipMemsetAsync(H2f0, 0, (size_t)B_ * XW * 2, stream);
    hipMemsetAsync(H2f1, 0, (size_t)B_ * XW * 2, stream);
    hipMemsetAsync(OUTB, 0, (size_t)T_ * B_ * XW * 2, stream);

    copy_hf<<<cdiv(B_ * H_, 256), 256, 0, stream>>>(h0, H0f1, H_, B_ * H_);
    copy_hf<<<cdiv(B_ * H_, 256), 256, 0, stream>>>(h1, H1f1, H_, B_ * H_);
    copy_hf<<<cdiv(B_ * E_, 256), 256, 0, stream>>>(h2, H2f1, E_, B_ * E_);
    copy_f32<<<cdiv(B_ * H_, 256), 256, 0, stream>>>(c0, c0b, B_ * H_);
    copy_f32<<<cdiv(B_ * H_, 256), 256, 0, stream>>>(c1, c1b, B_ * H_);
    copy_f32<<<cdiv(B_ * E_, 256), 256, 0, stream>>>(c2, c2b, B_ * E_);

    {
        int* flags = gbar;
        int* gen   = gbar + 448;
        void* args[] = {
            (void*)&XEf, (void*)&W0i, (void*)&W1i, (void*)&W2i,
            (void*)&b0i, (void*)&b1i, (void*)&b2i,
            (void*)&H0f0, (void*)&H0f1, (void*)&H1f0, (void*)&H1f1,
            (void*)&H2f0, (void*)&H2f1,
            (void*)&c0b, (void*)&c1b, (void*)&c2b, (void*)&OUTB,
            (void*)&flags, (void*)&gen
        };
        hipLaunchCooperativeKernel((void*)awd_persistent, dim3(NBLK), dim3(512),
                                   args, 0, stream);
    }

    decoder<<<dim3((V_ + 63) / 64, (T_ * B_) / 64), 256, 0, stream>>>(
        OUTB, Wdc, decb, (float*)d_out);
}

// Round 10
// 3893.998 us; speedup vs baseline: 12.8521x; 1.1106x over previous
//
#include <hip/hip_runtime.h>
#include <hip/hip_bf16.h>

typedef __hip_bfloat16 bf16;
typedef __attribute__((ext_vector_type(8))) short short8;
typedef __attribute__((ext_vector_type(4))) float f32x4;

#define T_ 256
#define B_ 64
#define V_ 10000
#define E_ 400
#define H_ 1152
#define KU 2304      // uniform padded K for weight buffers (72 kt of 32)
#define XW 416       // padded embedding width (13 kt)
#define KD 416       // decoder K (padded)
#define XET (XW*B_)  // shorts per timestep in frag-major
#define NBLK 169

#define MFMA16 __builtin_amdgcn_mfma_f32_16x16x32_bf16
#define ATL(p) __hip_atomic_load((p), __ATOMIC_RELAXED, __HIP_MEMORY_SCOPE_AGENT)
#define ATS(p, v) __hip_atomic_store((p), (v), __ATOMIC_RELAXED, __HIP_MEMORY_SCOPE_AGENT)
// opaque def: forbids rematerialization of the weight loads -> allocator must
// keep them register-resident (VGPR/AGPR) instead of re-reading via scratch
#define PIN(x) asm volatile("" : "+v"(x))

// ---------------- prep kernels ----------------

__global__ __launch_bounds__(256) void prep_wint(
    const float* __restrict__ s1, int w1,
    const float* __restrict__ s2, int off2, int w2, int Hl,
    bf16* __restrict__ dst, long total)
{
    long i = (long)blockIdx.x * 256 + threadIdx.x;
    if (i >= total) return;
    int r = (int)(i / KU), k = (int)(i % KU);
    int hcol = r >> 2, gate = r & 3;
    long srow = (long)gate * Hl + hcol;
    float v = 0.f;
    if (k < w1) v = s1[srow * w1 + k];
    else if (k >= off2 && k < off2 + w2) v = s2[srow * w2 + (k - off2)];
    dst[i] = __float2bfloat16(v);
}

__global__ __launch_bounds__(256) void prep_wcat(
    const float* __restrict__ s1, int w1,
    bf16* __restrict__ dst, int Ktot, long total)
{
    long i = (long)blockIdx.x * 256 + threadIdx.x;
    if (i >= total) return;
    int k = (int)(i % Ktot);
    long n = i / Ktot;
    dst[i] = __float2bfloat16(k < w1 ? s1[n * w1 + k] : 0.f);
}

__global__ __launch_bounds__(256) void bias_int(
    const float* __restrict__ a, const float* __restrict__ b,
    int Hl, float* __restrict__ d, int n)
{
    int r = blockIdx.x * 256 + threadIdx.x;
    if (r >= n) return;
    int hcol = r >> 2, gate = r & 3;
    d[r] = a[gate * Hl + hcol] + b[gate * Hl + hcol];
}

__global__ __launch_bounds__(256) void gather_xef(
    const int* __restrict__ x, const float* __restrict__ emb,
    bf16* __restrict__ XEf)
{
    long i = (long)blockIdx.x * 256 + threadIdx.x;
    if (i >= (long)T_ * B_ * XW) return;
    int k = (int)(i % XW);
    int b = (int)((i / XW) % B_);
    int t = (int)(i / ((long)XW * B_));
    float v = (k < E_) ? emb[(long)x[t * B_ + b] * E_ + k] : 0.f;
    XEf[(long)t * XET + (((k >> 3) * 64 + b) << 3) + (k & 7)] = __float2bfloat16(v);
}

__global__ __launch_bounds__(256) void copy_hf(
    const float* __restrict__ src, bf16* __restrict__ dst, int cols, int total)
{
    int i = blockIdx.x * 256 + threadIdx.x;
    if (i >= total) return;
    int k = i % cols, b = i / cols;
    dst[(((k >> 3) * 64 + b) << 3) + (k & 7)] = __float2bfloat16(src[(long)b * cols + k]);
}

__global__ __launch_bounds__(256) void copy_f32(
    const float* __restrict__ src, float* __restrict__ dst, int n)
{
    int i = blockIdx.x * 256 + threadIdx.x;
    if (i < n) dst[i] = src[i];
}

// ------------- fence-free grid barrier (write-through protocol) -------------
__device__ __forceinline__ void grid_bar(int* flags, int* gen, int phase) {
    asm volatile("s_waitcnt vmcnt(0)" ::: "memory");  // per-wave: h stores drained to L3
    __syncthreads();
    if (blockIdx.x == 0) {
        if (threadIdx.x < 64) {
            const int ln = threadIdx.x;
            if (ln == 0) ATS(&flags[0], phase);
            for (;;) {
                int f0 = (ln       < NBLK) ? ATL(&flags[ln])       : phase;
                int f1 = (ln + 64  < NBLK) ? ATL(&flags[ln + 64])  : phase;
                int f2 = (ln + 128 < NBLK) ? ATL(&flags[ln + 128]) : phase;
                if (__all(f0 >= phase && f1 >= phase && f2 >= phase)) break;
                __builtin_amdgcn_s_sleep(1);
            }
            if (ln == 0) ATS(gen, phase);
        }
    } else {
        if (threadIdx.x == 0) {
            ATS(&flags[blockIdx.x], phase);
            while (ATL(gen) < phase)
                __builtin_amdgcn_s_sleep(1);
        }
    }
    __syncthreads();
    asm volatile("" ::: "memory");   // no hoisting of next-phase loads above spin
}

// ------------- weight-stationary persistent LSTM, 8-way K split -------------
// 169 WGs: 0..71 L1, 72..143 L0, 144..168 L2. Each WG: 16 hidden cols
// (64 gate-interleaved rows). Wave w8 owns K-slice [w8*KT,(w8+1)*KT) kt,
// all 4 row-tiles. Weights PINNED in registers (opaque asm defs).
struct Frag4 { short8 f0, f1, f2, f3; };

__global__ __launch_bounds__(512, 2) void awd_persistent(
    const bf16* __restrict__ XEf,
    const bf16* __restrict__ W0, const bf16* __restrict__ W1, const bf16* __restrict__ W2,
    const float* __restrict__ b0, const float* __restrict__ b1, const float* __restrict__ b2,
    bf16* H0f0, bf16* H0f1, bf16* H1f0, bf16* H1f1, bf16* H2f0, bf16* H2f1,
    float* c0, float* c1, float* c2, bf16* OUTB,
    int* flags, int* gen)
{
    __shared__ float gsm[4][64][65];
    const int bid = blockIdx.x;
    const int tid = threadIdx.x;
    const int lane = tid & 63;
    const int w8 = tid >> 6;              // K-slice index 0..7
    const int lh = lane >> 4, l15 = lane & 15;
    const int boff8 = (lh * 64 + l15) * 8;

    int layer, grp;
    if (bid < 72)       { layer = 1; grp = bid; }
    else if (bid < 144) { layer = 0; grp = bid - 72; }
    else                { layer = 2; grp = bid - 144; }

    const bf16* Wp  = (layer == 0) ? W0 : (layer == 1) ? W1 : W2;
    const float* bias = (layer == 0) ? b0 : (layer == 1) ? b1 : b2;
    const float* cbuf = (layer == 0) ? c0 : (layer == 1) ? c1 : c2;
    const int Hl  = (layer == 2) ? 400 : 1152;
    const int bkt = (layer == 0) ? 13 : 36;   // kt where A switches A1 -> A2
    const int nkt = (layer == 1) ? 72 : 49;   // real kt count
    const int KT  = (layer == 1) ? 9  : 7;    // u-steps per wave
    const int kbase = w8 * KT;

    // ---- weights into registers (once), then PIN so they stay resident ----
    short8 wreg[9][4];
    #pragma unroll
    for (int u = 0; u < 9; ++u)
        if (u < KT) {
            #pragma unroll
            for (int rt = 0; rt < 4; ++rt) {
                int row = grp * 64 + rt * 16 + l15;
                int k   = (kbase + u) * 32 + lh * 8;
                wreg[u][rt] = *(const short8*)(Wp + (long)row * KU + k);
                PIN(wreg[u][rt]);
            }
        }

    float myb[2][4];
    #pragma unroll
    for (int e = 0; e < 2; ++e)
        #pragma unroll
        for (int g = 0; g < 4; ++g)
            myb[e][g] = bias[grp * 64 + (w8 + e * 8) * 4 + g];

    float creg[2];
    #pragma unroll
    for (int e = 0; e < 2; ++e)
        creg[e] = cbuf[(long)lane * Hl + grp * 16 + w8 + e * 8];

    for (int s = -1; s <= 256; ++s) {
        bool active = (layer == 0) ? (s <= 254)
                    : (layer == 1) ? (s >= 0 && s <= 255)
                                   : (s >= 1);
        if (active) {
            const int p = s & 1, q = p ^ 1;
            const bf16 *A1, *A2; bf16* hfW; bf16* ob = nullptr;
            if (layer == 0) {
                A1 = XEf + (long)(s + 1) * XET;
                A2 = p ? H0f1 : H0f0;
                hfW = q ? H0f1 : H0f0;
            } else if (layer == 1) {
                A1 = p ? H0f1 : H0f0;
                A2 = q ? H1f1 : H1f0;
                hfW = p ? H1f1 : H1f0;
            } else {
                A1 = q ? H1f1 : H1f0;
                A2 = p ? H2f1 : H2f0;
                hfW = q ? H2f1 : H2f0;
                ob = OUTB + (long)(s - 1) * B_ * XW;
            }

            // L3-coherent frag load: 4 batch-quarter frags of one kt block.
            // Frags at +0,+128,+256,+384 shorts = qp + 0/32/64/96 (8B units).
            auto loadf = [&](int u) -> Frag4 {
                const int ktg = kbase + u;
                const bf16* src; int ktL;
                if (ktg < bkt)      { src = A1; ktL = ktg; }
                else if (ktg < nkt) { src = A2; ktL = ktg - bkt; }
                else                { src = A1; ktL = 0; }   // pad: zero weights
                const unsigned long long* qp =
                    (const unsigned long long*)(src + ktL * 2048 + boff8);
                union { unsigned long long u2[2]; short8 s8; } a, b, c, d;
                a.u2[0] = ATL(qp);      a.u2[1] = ATL(qp + 1);
                b.u2[0] = ATL(qp + 32); b.u2[1] = ATL(qp + 33);
                c.u2[0] = ATL(qp + 64); c.u2[1] = ATL(qp + 65);
                d.u2[0] = ATL(qp + 96); d.u2[1] = ATL(qp + 97);
                Frag4 r; r.f0 = a.s8; r.f1 = b.s8; r.f2 = c.s8; r.f3 = d.s8;
                return r;
            };

            f32x4 acc[4][4];
            #pragma unroll
            for (int rt = 0; rt < 4; ++rt)
                #pragma unroll
                for (int m = 0; m < 4; ++m)
                    acc[rt][m] = (f32x4){0.f, 0.f, 0.f, 0.f};

            auto domfma = [&](int u, const Frag4& f) {
                #pragma unroll
                for (int rt = 0; rt < 4; ++rt) {
                    acc[rt][0] = MFMA16(wreg[u][rt], f.f0, acc[rt][0], 0, 0, 0);
                    acc[rt][1] = MFMA16(wreg[u][rt], f.f1, acc[rt][1], 0, 0, 0);
                    acc[rt][2] = MFMA16(wreg[u][rt], f.f2, acc[rt][2], 0, 0, 0);
                    acc[rt][3] = MFMA16(wreg[u][rt], f.f3, acc[rt][3], 0, 0, 0);
                }
            };

            // load-then-use (single Frag4 live: fits 256-reg budget with wreg)
            #pragma unroll
            for (int u = 0; u < 9; ++u)
                if (u < KT) {
                    Frag4 f = loadf(u);
                    domfma(u, f);
                }

            // partial-sum merge: waves 4-7 store, waves 0-3 accumulate
            __syncthreads();   // previous phase's gsm readers done
            if (w8 >= 4) {
                #pragma unroll
                for (int rt = 0; rt < 4; ++rt)
                    #pragma unroll
                    for (int m = 0; m < 4; ++m)
                        #pragma unroll
                        for (int r = 0; r < 4; ++r)
                            gsm[w8 - 4][rt * 16 + lh * 4 + r][m * 16 + l15] = acc[rt][m][r];
            }
            __syncthreads();
            if (w8 < 4) {
                #pragma unroll
                for (int rt = 0; rt < 4; ++rt)
                    #pragma unroll
                    for (int m = 0; m < 4; ++m)
                        #pragma unroll
                        for (int r = 0; r < 4; ++r)
                            gsm[w8][rt * 16 + lh * 4 + r][m * 16 + l15] += acc[rt][m][r];
            }
            __syncthreads();

            // nonlinearity: 16 cols x 64 batch, 2 per thread
            #pragma unroll
            for (int e = 0; e < 2; ++e) {
                int b = lane;
                int cl = w8 + e * 8;
                float gv[4];
                #pragma unroll
                for (int g = 0; g < 4; ++g)
                    gv[g] = gsm[0][cl * 4 + g][b] + gsm[1][cl * 4 + g][b]
                          + gsm[2][cl * 4 + g][b] + gsm[3][cl * 4 + g][b] + myb[e][g];
                int colG = grp * 16 + cl;
                float c_old = creg[e];
                float i_s = 1.f / (1.f + expf(-gv[0]));
                float f_s = 1.f / (1.f + expf(-gv[1]));
                float o_s = 1.f / (1.f + expf(-gv[3]));
                float c_new = f_s * c_old + i_s * tanhf(gv[2]);
                float hval = o_s * tanhf(c_new);
                creg[e] = c_new;
                bf16 hb = __float2bfloat16(hval);
                unsigned short hbits;
                __builtin_memcpy(&hbits, &hb, 2);
                ATS((unsigned short*)&hfW[(((colG >> 3) * 64 + b) << 3) + (colG & 7)], hbits);
                if (layer == 2) ob[(long)b * XW + colG] = hb;   // cross-kernel only: plain
            }
        }
        grid_bar(flags, gen, s + 2);
    }
}

// ---------------- decoder GEMM ----------------
__global__ __launch_bounds__(256) void decoder(
    const bf16* __restrict__ A, const bf16* __restrict__ W,
    const float* __restrict__ bias, float* __restrict__ out)
{
    const int tid = threadIdx.x;
    const int lane = tid & 63;
    const int w = tid >> 6;
    const int n0 = blockIdx.x * 64;
    const int m0 = blockIdx.y * 64 + w * 16;
    const int c16 = lane & 15;
    const int kg = lane >> 4;

    f32x4 acc[4];
    for (int i = 0; i < 4; ++i) acc[i] = (f32x4){0.f, 0.f, 0.f, 0.f};

    const bf16* arow = A + (long)(m0 + c16) * KD + kg * 8;
    #pragma unroll
    for (int kt = 0; kt < 13; ++kt) {
        short8 af = *(const short8*)(arow + kt * 32);
        #pragma unroll
        for (int ns = 0; ns < 4; ++ns) {
            int n = n0 + ns * 16 + c16;
            if (n > V_ - 1) n = V_ - 1;
            short8 bfr = *(const short8*)(W + (long)n * KD + kt * 32 + kg * 8);
            acc[ns] = MFMA16(af, bfr, acc[ns], 0, 0, 0);
        }
    }

    #pragma unroll
    for (int ns = 0; ns < 4; ++ns) {
        int col = n0 + ns * 16 + c16;
        if (col < V_) {
            float bv = bias[col];
            #pragma unroll
            for (int r = 0; r < 4; ++r) {
                int row = m0 + kg * 4 + r;
                out[(size_t)row * V_ + col] = acc[ns][r] + bv;
            }
        }
    }
}

// ---------------- host ----------------

extern "C" void kernel_launch(void* const* d_in, const int* in_sizes, int n_in,
                              void* d_out, int out_size, void* d_ws, size_t ws_size,
                              hipStream_t stream)
{
    const int*   x    = (const int*)d_in[0];
    const float* h0   = (const float*)d_in[1];
    const float* h1   = (const float*)d_in[2];
    const float* h2   = (const float*)d_in[3];
    const float* c0   = (const float*)d_in[4];
    const float* c1   = (const float*)d_in[5];
    const float* c2   = (const float*)d_in[6];
    const float* emb  = (const float*)d_in[7];
    const float* Wih0 = (const float*)d_in[8];
    const float* Whh0 = (const float*)d_in[9];
    const float* bih0 = (const float*)d_in[10];
    const float* bhh0 = (const float*)d_in[11];
    const float* Wih1 = (const float*)d_in[12];
    const float* Whh1 = (const float*)d_in[13];
    const float* bih1 = (const float*)d_in[14];
    const float* bhh1 = (const float*)d_in[15];
    const float* Wih2 = (const float*)d_in[16];
    const float* Whh2 = (const float*)d_in[17];
    const float* bih2 = (const float*)d_in[18];
    const float* bhh2 = (const float*)d_in[19];
    const float* decW = (const float*)d_in[20];
    const float* decb = (const float*)d_in[21];

    char* wsb = (char*)d_ws;
    size_t off = 0;
    auto alloc = [&](size_t bytes) -> void* {
        void* ptr = wsb + off;
        off = (off + bytes + 255) & ~(size_t)255;
        return ptr;
    };

    bf16* W0i = (bf16*)alloc((size_t)4608 * KU * 2);
    bf16* W1i = (bf16*)alloc((size_t)4608 * KU * 2);
    bf16* W2i = (bf16*)alloc((size_t)1600 * KU * 2);
    bf16* Wdc = (bf16*)alloc((size_t)V_ * KD * 2);
    float* b0i = (float*)alloc(4608 * 4);
    float* b1i = (float*)alloc(4608 * 4);
    float* b2i = (float*)alloc(1600 * 4);
    bf16* XEf = (bf16*)alloc((size_t)T_ * XET * 2);
    bf16* H0f0 = (bf16*)alloc((size_t)B_ * H_ * 2);
    bf16* H0f1 = (bf16*)alloc((size_t)B_ * H_ * 2);
    bf16* H1f0 = (bf16*)alloc((size_t)B_ * H_ * 2);
    bf16* H1f1 = (bf16*)alloc((size_t)B_ * H_ * 2);
    bf16* H2f0 = (bf16*)alloc((size_t)B_ * XW * 2);
    bf16* H2f1 = (bf16*)alloc((size_t)B_ * XW * 2);
    float* c0b = (float*)alloc((size_t)B_ * H_ * 4);
    float* c1b = (float*)alloc((size_t)B_ * H_ * 4);
    float* c2b = (float*)alloc((size_t)B_ * E_ * 4);
    bf16* OUTB = (bf16*)alloc((size_t)T_ * B_ * XW * 2);
    int* gbar = (int*)alloc(2048);   // flags[0..168]; gen at +448 ints

    auto cdiv = [](long a, long b) { return (int)((a + b - 1) / b); };

    hipMemsetAsync(gbar, 0, 2048, stream);

    prep_wint<<<cdiv(4608L * KU, 256), 256, 0, stream>>>(Wih0, 400,  Whh0, 416,  1152, 1152, W0i, 4608L * KU);
    prep_wint<<<cdiv(4608L * KU, 256), 256, 0, stream>>>(Wih1, 1152, Whh1, 1152, 1152, 1152, W1i, 4608L * KU);
    prep_wint<<<cdiv(1600L * KU, 256), 256, 0, stream>>>(Wih2, 1152, Whh2, 1152, 400,  400,  W2i, 1600L * KU);
    prep_wcat<<<cdiv((long)V_ * KD, 256), 256, 0, stream>>>(decW, 400, Wdc, KD, (long)V_ * KD);
    bias_int<<<cdiv(4608, 256), 256, 0, stream>>>(bih0, bhh0, 1152, b0i, 4608);
    bias_int<<<cdiv(4608, 256), 256, 0, stream>>>(bih1, bhh1, 1152, b1i, 4608);
    bias_int<<<cdiv(1600, 256), 256, 0, stream>>>(bih2, bhh2, 400,  b2i, 1600);
    gather_xef<<<cdiv((long)T_ * B_ * XW, 256), 256, 0, stream>>>(x, emb, XEf);

    hipMemsetAsync(H2f0, 0, (size_t)B_ * XW * 2, stream);
    hipMemsetAsync(H2f1, 0, (size_t)B_ * XW * 2, stream);
    hipMemsetAsync(OUTB, 0, (size_t)T_ * B_ * XW * 2, stream);

    copy_hf<<<cdiv(B_ * H_, 256), 256, 0, stream>>>(h0, H0f1, H_, B_ * H_);
    copy_hf<<<cdiv(B_ * H_, 256), 256, 0, stream>>>(h1, H1f1, H_, B_ * H_);
    copy_hf<<<cdiv(B_ * E_, 256), 256, 0, stream>>>(h2, H2f1, E_, B_ * E_);
    copy_f32<<<cdiv(B_ * H_, 256), 256, 0, stream>>>(c0, c0b, B_ * H_);
    copy_f32<<<cdiv(B_ * H_, 256), 256, 0, stream>>>(c1, c1b, B_ * H_);
    copy_f32<<<cdiv(B_ * E_, 256), 256, 0, stream>>>(c2, c2b, B_ * E_);

    {
        int* flags = gbar;
        int* gen   = gbar + 448;
        void* args[] = {
            (void*)&XEf, (void*)&W0i, (void*)&W1i, (void*)&W2i,
            (void*)&b0i, (void*)&b1i, (void*)&b2i,
            (void*)&H0f0, (void*)&H0f1, (void*)&H1f0, (void*)&H1f1,
            (void*)&H2f0, (void*)&H2f1,
            (void*)&c0b, (void*)&c1b, (void*)&c2b, (void*)&OUTB,
            (void*)&flags, (void*)&gen
        };
        hipLaunchCooperativeKernel((void*)awd_persistent, dim3(NBLK), dim3(512),
                                   args, 0, stream);
    }

    decoder<<<dim3((V_ + 63) / 64, (T_ * B_) / 64), 256, 0, stream>>>(
        OUTB, Wdc, decb, (float*)d_out);
}

// Round 11
// 3643.588 us; speedup vs baseline: 13.7354x; 1.0687x over previous
//
#include <hip/hip_runtime.h>
#include <hip/hip_bf16.h>

typedef __hip_bfloat16 bf16;
typedef __attribute__((ext_vector_type(8))) short short8;
typedef __attribute__((ext_vector_type(4))) float f32x4;

#define T_ 256
#define B_ 64
#define V_ 10000
#define E_ 400
#define H_ 1152
#define KU 2304      // uniform padded K for weight buffers (72 kt of 32)
#define XW 416       // padded embedding width (13 kt)
#define KD 416       // decoder K (padded)
#define XET (XW*B_)  // shorts per timestep in frag-major
#define NBLK 169

#define MFMA16 __builtin_amdgcn_mfma_f32_16x16x32_bf16
#define ATL(p) __hip_atomic_load((p), __ATOMIC_RELAXED, __HIP_MEMORY_SCOPE_AGENT)
#define ATS(p, v) __hip_atomic_store((p), (v), __ATOMIC_RELAXED, __HIP_MEMORY_SCOPE_AGENT)
// opaque def: forbids rematerialization of the weight loads -> allocator must
// keep them register-resident (VGPR/AGPR) instead of re-loading each phase
#define PIN(x) asm volatile("" : "+v"(x))

// ---------------- prep kernels ----------------

__global__ __launch_bounds__(256) void prep_wint(
    const float* __restrict__ s1, int w1,
    const float* __restrict__ s2, int off2, int w2, int Hl,
    bf16* __restrict__ dst, long total)
{
    long i = (long)blockIdx.x * 256 + threadIdx.x;
    if (i >= total) return;
    int r = (int)(i / KU), k = (int)(i % KU);
    int hcol = r >> 2, gate = r & 3;
    long srow = (long)gate * Hl + hcol;
    float v = 0.f;
    if (k < w1) v = s1[srow * w1 + k];
    else if (k >= off2 && k < off2 + w2) v = s2[srow * w2 + (k - off2)];
    dst[i] = __float2bfloat16(v);
}

__global__ __launch_bounds__(256) void prep_wcat(
    const float* __restrict__ s1, int w1,
    bf16* __restrict__ dst, int Ktot, long total)
{
    long i = (long)blockIdx.x * 256 + threadIdx.x;
    if (i >= total) return;
    int k = (int)(i % Ktot);
    long n = i / Ktot;
    dst[i] = __float2bfloat16(k < w1 ? s1[n * w1 + k] : 0.f);
}

__global__ __launch_bounds__(256) void bias_int(
    const float* __restrict__ a, const float* __restrict__ b,
    int Hl, float* __restrict__ d, int n)
{
    int r = blockIdx.x * 256 + threadIdx.x;
    if (r >= n) return;
    int hcol = r >> 2, gate = r & 3;
    d[r] = a[gate * Hl + hcol] + b[gate * Hl + hcol];
}

__global__ __launch_bounds__(256) void gather_xef(
    const int* __restrict__ x, const float* __restrict__ emb,
    bf16* __restrict__ XEf)
{
    long i = (long)blockIdx.x * 256 + threadIdx.x;
    if (i >= (long)T_ * B_ * XW) return;
    int k = (int)(i % XW);
    int b = (int)((i / XW) % B_);
    int t = (int)(i / ((long)XW * B_));
    float v = (k < E_) ? emb[(long)x[t * B_ + b] * E_ + k] : 0.f;
    XEf[(long)t * XET + (((k >> 3) * 64 + b) << 3) + (k & 7)] = __float2bfloat16(v);
}

__global__ __launch_bounds__(256) void copy_hf(
    const float* __restrict__ src, bf16* __restrict__ dst, int cols, int total)
{
    int i = blockIdx.x * 256 + threadIdx.x;
    if (i >= total) return;
    int k = i % cols, b = i / cols;
    dst[(((k >> 3) * 64 + b) << 3) + (k & 7)] = __float2bfloat16(src[(long)b * cols + k]);
}

__global__ __launch_bounds__(256) void copy_f32(
    const float* __restrict__ src, float* __restrict__ dst, int n)
{
    int i = blockIdx.x * 256 + threadIdx.x;
    if (i < n) dst[i] = src[i];
}

// ---- grid barrier: write-through stores + acquire-invalidate on readers ----
// Writers: h stores are agent-relaxed write-through (L3), drained per-wave by
// vmcnt(0). Readers: plain CACHED loads; after the barrier each WG's tid0
// executes an agent-acquire fence (L1/L2 invalidate, NO writeback scan) so
// the first read per XCD refills L2 from L3 and the other ~20 WGs hit L2.
__device__ __forceinline__ void grid_bar(int* flags, int* gen, int phase) {
    asm volatile("s_waitcnt vmcnt(0)" ::: "memory");  // per-wave: h stores drained to L3
    __syncthreads();
    if (blockIdx.x == 0) {
        if (threadIdx.x < 64) {
            const int ln = threadIdx.x;
            if (ln == 0) ATS(&flags[0], phase);
            for (;;) {
                int f0 = (ln       < NBLK) ? ATL(&flags[ln])       : phase;
                int f1 = (ln + 64  < NBLK) ? ATL(&flags[ln + 64])  : phase;
                int f2 = (ln + 128 < NBLK) ? ATL(&flags[ln + 128]) : phase;
                if (__all(f0 >= phase && f1 >= phase && f2 >= phase)) break;
                __builtin_amdgcn_s_sleep(1);
            }
            if (ln == 0) {
                ATS(gen, phase);
                __builtin_amdgcn_fence(__ATOMIC_ACQUIRE, "agent");  // inv L1/L2
            }
        }
    } else {
        if (threadIdx.x == 0) {
            ATS(&flags[blockIdx.x], phase);
            while (ATL(gen) < phase)
                __builtin_amdgcn_s_sleep(1);
            __builtin_amdgcn_fence(__ATOMIC_ACQUIRE, "agent");      // inv L1/L2
        }
    }
    __syncthreads();
    asm volatile("" ::: "memory");   // no hoisting of next-phase loads above spin
}

// ------------- weight-stationary persistent LSTM, 8-way K split -------------
// 169 WGs: 0..71 L1, 72..143 L0, 144..168 L2. Each WG: 16 hidden cols
// (64 gate-interleaved rows). Wave w8 owns K-slice [w8*KT,(w8+1)*KT) kt,
// all 4 row-tiles. Weights PINNED in registers (opaque asm defs).
struct Frag4 { short8 f0, f1, f2, f3; };

__global__ __launch_bounds__(512, 2) void awd_persistent(
    const bf16* __restrict__ XEf,
    const bf16* __restrict__ W0, const bf16* __restrict__ W1, const bf16* __restrict__ W2,
    const float* __restrict__ b0, const float* __restrict__ b1, const float* __restrict__ b2,
    bf16* H0f0, bf16* H0f1, bf16* H1f0, bf16* H1f1, bf16* H2f0, bf16* H2f1,
    float* c0, float* c1, float* c2, bf16* OUTB,
    int* flags, int* gen)
{
    __shared__ float gsm[4][64][65];
    const int bid = blockIdx.x;
    const int tid = threadIdx.x;
    const int lane = tid & 63;
    const int w8 = tid >> 6;              // K-slice index 0..7
    const int lh = lane >> 4, l15 = lane & 15;
    const int boff8 = (lh * 64 + l15) * 8;

    int layer, grp;
    if (bid < 72)       { layer = 1; grp = bid; }
    else if (bid < 144) { layer = 0; grp = bid - 72; }
    else                { layer = 2; grp = bid - 144; }

    const bf16* Wp  = (layer == 0) ? W0 : (layer == 1) ? W1 : W2;
    const float* bias = (layer == 0) ? b0 : (layer == 1) ? b1 : b2;
    const float* cbuf = (layer == 0) ? c0 : (layer == 1) ? c1 : c2;
    const int Hl  = (layer == 2) ? 400 : 1152;
    const int bkt = (layer == 0) ? 13 : 36;   // kt where A switches A1 -> A2
    const int nkt = (layer == 1) ? 72 : 49;   // real kt count
    const int KT  = (layer == 1) ? 9  : 7;    // u-steps per wave
    const int kbase = w8 * KT;

    // ---- weights into registers (once), then PIN so they stay resident ----
    short8 wreg[9][4];
    #pragma unroll
    for (int u = 0; u < 9; ++u)
        if (u < KT) {
            #pragma unroll
            for (int rt = 0; rt < 4; ++rt) {
                int row = grp * 64 + rt * 16 + l15;
                int k   = (kbase + u) * 32 + lh * 8;
                wreg[u][rt] = *(const short8*)(Wp + (long)row * KU + k);
                PIN(wreg[u][rt]);
            }
        }

    float myb[2][4];
    #pragma unroll
    for (int e = 0; e < 2; ++e)
        #pragma unroll
        for (int g = 0; g < 4; ++g)
            myb[e][g] = bias[grp * 64 + (w8 + e * 8) * 4 + g];

    float creg[2];
    #pragma unroll
    for (int e = 0; e < 2; ++e)
        creg[e] = cbuf[(long)lane * Hl + grp * 16 + w8 + e * 8];

    for (int s = -1; s <= 256; ++s) {
        bool active = (layer == 0) ? (s <= 254)
                    : (layer == 1) ? (s >= 0 && s <= 255)
                                   : (s >= 1);
        if (active) {
            const int p = s & 1, q = p ^ 1;
            const bf16 *A1, *A2; bf16* hfW; bf16* ob = nullptr;
            if (layer == 0) {
                A1 = XEf + (long)(s + 1) * XET;
                A2 = p ? H0f1 : H0f0;
                hfW = q ? H0f1 : H0f0;
            } else if (layer == 1) {
                A1 = p ? H0f1 : H0f0;
                A2 = q ? H1f1 : H1f0;
                hfW = p ? H1f1 : H1f0;
            } else {
                A1 = q ? H1f1 : H1f0;
                A2 = p ? H2f1 : H2f0;
                hfW = q ? H2f1 : H2f0;
                ob = OUTB + (long)(s - 1) * B_ * XW;
            }

            // plain CACHED frag load (L2 serves the 169-WG fan-out after inv);
            // frags at +0,+128,+256,+384 bf16 elements
            auto loadf = [&](int u) -> Frag4 {
                const int ktg = kbase + u;
                const bf16* src; int ktL;
                if (ktg < bkt)      { src = A1; ktL = ktg; }
                else if (ktg < nkt) { src = A2; ktL = ktg - bkt; }
                else                { src = A1; ktL = 0; }   // pad: zero weights
                const bf16* pB = src + ktL * 2048 + boff8;
                Frag4 r;
                r.f0 = *(const short8*)(pB);
                r.f1 = *(const short8*)(pB + 128);
                r.f2 = *(const short8*)(pB + 256);
                r.f3 = *(const short8*)(pB + 384);
                return r;
            };

            f32x4 acc[4][4];
            #pragma unroll
            for (int rt = 0; rt < 4; ++rt)
                #pragma unroll
                for (int m = 0; m < 4; ++m)
                    acc[rt][m] = (f32x4){0.f, 0.f, 0.f, 0.f};

            auto domfma = [&](int u, const Frag4& f) {
                #pragma unroll
                for (int rt = 0; rt < 4; ++rt) {
                    acc[rt][0] = MFMA16(wreg[u][rt], f.f0, acc[rt][0], 0, 0, 0);
                    acc[rt][1] = MFMA16(wreg[u][rt], f.f1, acc[rt][1], 0, 0, 0);
                    acc[rt][2] = MFMA16(wreg[u][rt], f.f2, acc[rt][2], 0, 0, 0);
                    acc[rt][3] = MFMA16(wreg[u][rt], f.f3, acc[rt][3], 0, 0, 0);
                }
            };

            // load-then-use (single Frag4 live: fits register budget with wreg)
            #pragma unroll
            for (int u = 0; u < 9; ++u)
                if (u < KT) {
                    Frag4 f = loadf(u);
                    domfma(u, f);
                }

            // partial-sum merge: waves 4-7 store, waves 0-3 accumulate
            __syncthreads();   // previous phase's gsm readers done
            if (w8 >= 4) {
                #pragma unroll
                for (int rt = 0; rt < 4; ++rt)
                    #pragma unroll
                    for (int m = 0; m < 4; ++m)
                        #pragma unroll
                        for (int r = 0; r < 4; ++r)
                            gsm[w8 - 4][rt * 16 + lh * 4 + r][m * 16 + l15] = acc[rt][m][r];
            }
            __syncthreads();
            if (w8 < 4) {
                #pragma unroll
                for (int rt = 0; rt < 4; ++rt)
                    #pragma unroll
                    for (int m = 0; m < 4; ++m)
                        #pragma unroll
                        for (int r = 0; r < 4; ++r)
                            gsm[w8][rt * 16 + lh * 4 + r][m * 16 + l15] += acc[rt][m][r];
            }
            __syncthreads();

            // nonlinearity: 16 cols x 64 batch, 2 per thread
            #pragma unroll
            for (int e = 0; e < 2; ++e) {
                int b = lane;
                int cl = w8 + e * 8;
                float gv[4];
                #pragma unroll
                for (int g = 0; g < 4; ++g)
                    gv[g] = gsm[0][cl * 4 + g][b] + gsm[1][cl * 4 + g][b]
                          + gsm[2][cl * 4 + g][b] + gsm[3][cl * 4 + g][b] + myb[e][g];
                int colG = grp * 16 + cl;
                float c_old = creg[e];
                float i_s = 1.f / (1.f + expf(-gv[0]));
                float f_s = 1.f / (1.f + expf(-gv[1]));
                float o_s = 1.f / (1.f + expf(-gv[3]));
                float c_new = f_s * c_old + i_s * tanhf(gv[2]);
                float hval = o_s * tanhf(c_new);
                creg[e] = c_new;
                bf16 hb = __float2bfloat16(hval);
                unsigned short hbits;
                __builtin_memcpy(&hbits, &hb, 2);
                ATS((unsigned short*)&hfW[(((colG >> 3) * 64 + b) << 3) + (colG & 7)], hbits);
                if (layer == 2) ob[(long)b * XW + colG] = hb;   // cross-kernel only: plain
            }
        }
        grid_bar(flags, gen, s + 2);
    }
}

// ---------------- decoder GEMM ----------------
__global__ __launch_bounds__(256) void decoder(
    const bf16* __restrict__ A, const bf16* __restrict__ W,
    const float* __restrict__ bias, float* __restrict__ out)
{
    const int tid = threadIdx.x;
    const int lane = tid & 63;
    const int w = tid >> 6;
    const int n0 = blockIdx.x * 64;
    const int m0 = blockIdx.y * 64 + w * 16;
    const int c16 = lane & 15;
    const int kg = lane >> 4;

    f32x4 acc[4];
    for (int i = 0; i < 4; ++i) acc[i] = (f32x4){0.f, 0.f, 0.f, 0.f};

    const bf16* arow = A + (long)(m0 + c16) * KD + kg * 8;
    #pragma unroll
    for (int kt = 0; kt < 13; ++kt) {
        short8 af = *(const short8*)(arow + kt * 32);
        #pragma unroll
        for (int ns = 0; ns < 4; ++ns) {
            int n = n0 + ns * 16 + c16;
            if (n > V_ - 1) n = V_ - 1;
            short8 bfr = *(const short8*)(W + (long)n * KD + kt * 32 + kg * 8);
            acc[ns] = MFMA16(af, bfr, acc[ns], 0, 0, 0);
        }
    }

    #pragma unroll
    for (int ns = 0; ns < 4; ++ns) {
        int col = n0 + ns * 16 + c16;
        if (col < V_) {
            float bv = bias[col];
            #pragma unroll
            for (int r = 0; r < 4; ++r) {
                int row = m0 + kg * 4 + r;
                out[(size_t)row * V_ + col] = acc[ns][r] + bv;
            }
        }
    }
}

// ---------------- host ----------------

extern "C" void kernel_launch(void* const* d_in, const int* in_sizes, int n_in,
                              void* d_out, int out_size, void* d_ws, size_t ws_size,
                              hipStream_t stream)
{
    const int*   x    = (const int*)d_in[0];
    const float* h0   = (const float*)d_in[1];
    const float* h1   = (const float*)d_in[2];
    const float* h2   = (const float*)d_in[3];
    const float* c0   = (const float*)d_in[4];
    const float* c1   = (const float*)d_in[5];
    const float* c2   = (const float*)d_in[6];
    const float* emb  = (const float*)d_in[7];
    const float* Wih0 = (const float*)d_in[8];
    const float* Whh0 = (const float*)d_in[9];
    const float* bih0 = (const float*)d_in[10];
    const float* bhh0 = (const float*)d_in[11];
    const float* Wih1 = (const float*)d_in[12];
    const float* Whh1 = (const float*)d_in[13];
    const float* bih1 = (const float*)d_in[14];
    const float* bhh1 = (const float*)d_in[15];
    const float* Wih2 = (const float*)d_in[16];
    const float* Whh2 = (const float*)d_in[17];
    const float* bih2 = (const float*)d_in[18];
    const float* bhh2 = (const float*)d_in[19];
    const float* decW = (const float*)d_in[20];
    const float* decb = (const float*)d_in[21];

    char* wsb = (char*)d_ws;
    size_t off = 0;
    auto alloc = [&](size_t bytes) -> void* {
        void* ptr = wsb + off;
        off = (off + bytes + 255) & ~(size_t)255;
        return ptr;
    };

    bf16* W0i = (bf16*)alloc((size_t)4608 * KU * 2);
    bf16* W1i = (bf16*)alloc((size_t)4608 * KU * 2);
    bf16* W2i = (bf16*)alloc((size_t)1600 * KU * 2);
    bf16* Wdc = (bf16*)alloc((size_t)V_ * KD * 2);
    float* b0i = (float*)alloc(4608 * 4);
    float* b1i = (float*)alloc(4608 * 4);
    float* b2i = (float*)alloc(1600 * 4);
    bf16* XEf = (bf16*)alloc((size_t)T_ * XET * 2);
    bf16* H0f0 = (bf16*)alloc((size_t)B_ * H_ * 2);
    bf16* H0f1 = (bf16*)alloc((size_t)B_ * H_ * 2);
    bf16* H1f0 = (bf16*)alloc((size_t)B_ * H_ * 2);
    bf16* H1f1 = (bf16*)alloc((size_t)B_ * H_ * 2);
    bf16* H2f0 = (bf16*)alloc((size_t)B_ * XW * 2);
    bf16* H2f1 = (bf16*)alloc((size_t)B_ * XW * 2);
    float* c0b = (float*)alloc((size_t)B_ * H_ * 4);
    float* c1b = (float*)alloc((size_t)B_ * H_ * 4);
    float* c2b = (float*)alloc((size_t)B_ * E_ * 4);
    bf16* OUTB = (bf16*)alloc((size_t)T_ * B_ * XW * 2);
    int* gbar = (int*)alloc(2048);   // flags[0..168]; gen at +448 ints

    auto cdiv = [](long a, long b) { return (int)((a + b - 1) / b); };

    hipMemsetAsync(gbar, 0, 2048, stream);

    prep_wint<<<cdiv(4608L * KU, 256), 256, 0, stream>>>(Wih0, 400,  Whh0, 416,  1152, 1152, W0i, 4608L * KU);
    prep_wint<<<cdiv(4608L * KU, 256), 256, 0, stream>>>(Wih1, 1152, Whh1, 1152, 1152, 1152, W1i, 4608L * KU);
    prep_wint<<<cdiv(1600L * KU, 256), 256, 0, stream>>>(Wih2, 1152, Whh2, 1152, 400,  400,  W2i, 1600L * KU);
    prep_wcat<<<cdiv((long)V_ * KD, 256), 256, 0, stream>>>(decW, 400, Wdc, KD, (long)V_ * KD);
    bias_int<<<cdiv(4608, 256), 256, 0, stream>>>(bih0, bhh0, 1152, b0i, 4608);
    bias_int<<<cdiv(4608, 256), 256, 0, stream>>>(bih1, bhh1, 1152, b1i, 4608);
    bias_int<<<cdiv(1600, 256), 256, 0, stream>>>(bih2, bhh2, 400,  b2i, 1600);
    gather_xef<<<cdiv((long)T_ * B_ * XW, 256), 256, 0, stream>>>(x, emb, XEf);

    hipMemsetAsync(H2f0, 0, (size_t)B_ * XW * 2, stream);
    hipMemsetAsync(H2f1, 0, (size_t)B_ * XW * 2, stream);
    hipMemsetAsync(OUTB, 0, (size_t)T_ * B_ * XW * 2, stream);

    copy_hf<<<cdiv(B_ * H_, 256), 256, 0, stream>>>(h0, H0f1, H_, B_ * H_);
    copy_hf<<<cdiv(B_ * H_, 256), 256, 0, stream>>>(h1, H1f1, H_, B_ * H_);
    copy_hf<<<cdiv(B_ * E_, 256), 256, 0, stream>>>(h2, H2f1, E_, B_ * E_);
    copy_f32<<<cdiv(B_ * H_, 256), 256, 0, stream>>>(c0, c0b, B_ * H_);
    copy_f32<<<cdiv(B_ * H_, 256), 256, 0, stream>>>(c1, c1b, B_ * H_);
    copy_f32<<<cdiv(B_ * E_, 256), 256, 0, stream>>>(c2, c2b, B_ * E_);

    {
        int* flags = gbar;
        int* gen   = gbar + 448;
        void* args[] = {
            (void*)&XEf, (void*)&W0i, (void*)&W1i, (void*)&W2i,
            (void*)&b0i, (void*)&b1i, (void*)&b2i,
            (void*)&H0f0, (void*)&H0f1, (void*)&H1f0, (void*)&H1f1,
            (void*)&H2f0, (void*)&H2f1,
            (void*)&c0b, (void*)&c1b, (void*)&c2b, (void*)&OUTB,
            (void*)&flags, (void*)&gen
        };
        hipLaunchCooperativeKernel((void*)awd_persistent, dim3(NBLK), dim3(512),
                                   args, 0, stream);
    }

    decoder<<<dim3((V_ + 63) / 64, (T_ * B_) / 64), 256, 0, stream>>>(
        OUTB, Wdc, decb, (float*)d_out);
}